// Round 4
// baseline (525.862 us; speedup 1.0000x reference)
//
#include <hip/hip_runtime.h>
#include <hip/hip_bf16.h>
#include <cstdint>

#define BB 8
#define NV 1024
#define HH 128
#define DH 32
#define NCOE 50
#define NSC 4

// Wb segment offsets (elements)
#define WOFF_EIG 0
#define WOFF_QKV 16384
#define WOFF_OUT 65536
#define WOFF_F1  81920
#define WOFF_F2  98304
#define WB_ELEMS 114688

typedef __attribute__((ext_vector_type(8))) short short8;
typedef __attribute__((ext_vector_type(4))) float f32x4;

__device__ __forceinline__ ushort f2bf(float f) {
    uint32_t x = __float_as_uint(f);
    uint32_t r = x + 0x7FFFu + ((x >> 16) & 1u);
    return (ushort)(r >> 16);
}

#define GLDS(gp, lp) __builtin_amdgcn_global_load_lds((const __attribute__((address_space(1))) void*)(gp), (__attribute__((address_space(3))) void*)(lp), 16, 0, 0)

// ---------------- K0: weight convert f32 -> bf16, LDS-chunked layout [kt][r][32] ----------------
__global__ void k_wcvt(const float* __restrict__ eigw_W, const float* __restrict__ qkv_W,
                       const float* __restrict__ out_W, const float* __restrict__ f1W,
                       const float* __restrict__ f2W, ushort* __restrict__ Wb) {
    int idx = blockIdx.x * 256 + threadIdx.x;
    float v; int dst;
    if (idx < 16384) {                 // eigw cols 1..128
        int r = idx >> 7, k = idx & 127;
        v = eigw_W[r * 129 + 1 + k];
        dst = WOFF_EIG + (k >> 5) * 4096 + r * 32 + (k & 31);
    } else if (idx < 65536) {          // qkv_W, 3 chunks of 128 rows
        int l = idx - 16384; int c = l >> 14, rem = l & 16383;
        int r = rem >> 7, k = rem & 127;
        v = qkv_W[(size_t)(c * 128 + r) * 128 + k];
        dst = WOFF_QKV + c * 16384 + (k >> 5) * 4096 + r * 32 + (k & 31);
    } else if (idx < 81920) {          // out_W
        int l = idx - 65536; int r = l >> 7, k = l & 127;
        v = out_W[r * 128 + k];
        dst = WOFF_OUT + (k >> 5) * 4096 + r * 32 + (k & 31);
    } else if (idx < 98304) {          // ffn1_W
        int l = idx - 81920; int r = l >> 7, k = l & 127;
        v = f1W[r * 128 + k];
        dst = WOFF_F1 + (k >> 5) * 4096 + r * 32 + (k & 31);
    } else {                           // ffn2_W
        int l = idx - 98304; int r = l >> 7, k = l & 127;
        v = f2W[r * 128 + k];
        dst = WOFF_F2 + (k >> 5) * 4096 + r * 32 + (k & 31);
    }
    Wb[dst] = f2bf(v);
}

// ---------------- K1: sine encoding + eigw linear (MFMA) -> eig f32 [8192][128] ----------------
__global__ __launch_bounds__(256) void k_enc_sine(const float* __restrict__ ev, const ushort* __restrict__ Wb,
                                                  const float* __restrict__ eigw_W, const float* __restrict__ eigw_b,
                                                  float* __restrict__ eig) {
    __shared__ ushort As[16384];
    __shared__ ushort Bs[16384];
    int row0 = blockIdx.x * 128;
    int t = threadIdx.x, lane = t & 63, w = t >> 6;
    int wr = w >> 1, wc = w & 1;
#pragma unroll
    for (int p = 0; p < 8; ++p) {
        int ci = w * 8 + p;
        GLDS(Wb + WOFF_EIG + ci * 512 + lane * 8, Bs + ci * 512);
    }
    {
        int r = t >> 1, half = t & 1;
        float e = ev[row0 + r] * 100.0f;
#pragma unroll
        for (int ch = 0; ch < 8; ++ch) {
            short8 u;
#pragma unroll
            for (int l = 0; l < 8; ++l) {
                int j = ch * 8 + l;
                float div = expf((float)(2 * j) * -0.07195578415606394f);
                float pe = e * div;
                u[l] = (short)f2bf(half ? cosf(pe) : sinf(pe));
            }
            int k = half * 64 + ch * 8;
            *(short8*)(As + (k >> 5) * 4096 + r * 32 + (k & 31)) = u;
        }
    }
    __syncthreads();
    int cl = lane & 15, q = lane >> 4;
    f32x4 acc[4][4] = {};
#pragma unroll
    for (int kt = 0; kt < 4; ++kt) {
        const ushort* ap = As + kt * 4096 + (wr * 64 + cl) * 32 + q * 8;
        const ushort* bp = Bs + kt * 4096 + (wc * 64 + cl) * 32 + q * 8;
        short8 af[4], bfr[4];
#pragma unroll
        for (int i = 0; i < 4; ++i) af[i] = *(const short8*)(ap + i * 512);
#pragma unroll
        for (int j = 0; j < 4; ++j) bfr[j] = *(const short8*)(bp + j * 512);
#pragma unroll
        for (int i = 0; i < 4; ++i)
#pragma unroll
            for (int j = 0; j < 4; ++j)
                acc[i][j] = __builtin_amdgcn_mfma_f32_16x16x32_bf16(af[i], bfr[j], acc[i][j], 0, 0, 0);
    }
#pragma unroll
    for (int i = 0; i < 4; ++i) {
        int rbase = wr * 64 + i * 16 + q * 4;
        float er[4];
#pragma unroll
        for (int r = 0; r < 4; ++r) er[r] = ev[row0 + rbase + r];
#pragma unroll
        for (int j = 0; j < 4; ++j) {
            int col = wc * 64 + j * 16 + cl;
            float w0 = eigw_W[col * 129];
            float bv = eigw_b[col];
#pragma unroll
            for (int r = 0; r < 4; ++r)
                eig[(size_t)(row0 + rbase + r) * HH + col] = acc[i][j][r] + er[r] * w0 + bv;
        }
    }
}

// ---------------- K2: LN1 + QKV (MFMA) -> q/k/v bf16 head-major [bh][n][32] ----------------
__global__ __launch_bounds__(256) void k_enc_qkv(const float* __restrict__ eig, const float* __restrict__ g,
                                                 const float* __restrict__ be, const ushort* __restrict__ Wb,
                                                 const float* __restrict__ bias,
                                                 ushort* __restrict__ qb, ushort* __restrict__ kb, ushort* __restrict__ vb) {
    __shared__ ushort As[16384];
    __shared__ ushort Bs[16384];
    int row0 = blockIdx.x * 128;
    int t = threadIdx.x, lane = t & 63, w = t >> 6;
    int wr = w >> 1, wc = w & 1;
    {
        int r = t >> 1, half = t & 1;
        const float4* rowp = (const float4*)(eig + (size_t)(row0 + r) * HH + half * 64);
        float4 v[16];
        float s = 0.f, s2 = 0.f;
#pragma unroll
        for (int i = 0; i < 16; ++i) {
            float4 a = rowp[i]; v[i] = a;
            s += a.x + a.y + a.z + a.w;
            s2 += a.x * a.x + a.y * a.y + a.z * a.z + a.w * a.w;
        }
        s += __shfl_xor(s, 1); s2 += __shfl_xor(s2, 1);
        float mean = s * 0.0078125f;
        float var = s2 * 0.0078125f - mean * mean;
        float rstd = rsqrtf(var + 1e-5f);
        const float4* g4 = (const float4*)(g + half * 64);
        const float4* b4 = (const float4*)(be + half * 64);
#pragma unroll
        for (int ch = 0; ch < 8; ++ch) {
            float4 a = v[2 * ch], b2 = v[2 * ch + 1];
            float4 ga = g4[2 * ch], gb = g4[2 * ch + 1];
            float4 ba = b4[2 * ch], bb = b4[2 * ch + 1];
            short8 u;
            u[0] = (short)f2bf((a.x - mean) * rstd * ga.x + ba.x);
            u[1] = (short)f2bf((a.y - mean) * rstd * ga.y + ba.y);
            u[2] = (short)f2bf((a.z - mean) * rstd * ga.z + ba.z);
            u[3] = (short)f2bf((a.w - mean) * rstd * ga.w + ba.w);
            u[4] = (short)f2bf((b2.x - mean) * rstd * gb.x + bb.x);
            u[5] = (short)f2bf((b2.y - mean) * rstd * gb.y + bb.y);
            u[6] = (short)f2bf((b2.z - mean) * rstd * gb.z + bb.z);
            u[7] = (short)f2bf((b2.w - mean) * rstd * gb.w + bb.w);
            int k = half * 64 + ch * 8;
            *(short8*)(As + (k >> 5) * 4096 + r * 32 + (k & 31)) = u;
        }
    }
    int cl = lane & 15, q = lane >> 4;
    int bidx = row0 >> 10, nbase = row0 & (NV - 1);
    ushort* dsts[3] = {qb, kb, vb};
#pragma unroll 1
    for (int c = 0; c < 3; ++c) {
        __syncthreads();
#pragma unroll
        for (int p = 0; p < 8; ++p) {
            int ci = w * 8 + p;
            GLDS(Wb + WOFF_QKV + c * 16384 + ci * 512 + lane * 8, Bs + ci * 512);
        }
        __syncthreads();
        f32x4 acc[4][4] = {};
#pragma unroll
        for (int kt = 0; kt < 4; ++kt) {
            const ushort* ap = As + kt * 4096 + (wr * 64 + cl) * 32 + q * 8;
            const ushort* bp = Bs + kt * 4096 + (wc * 64 + cl) * 32 + q * 8;
            short8 af[4], bfr[4];
#pragma unroll
            for (int i = 0; i < 4; ++i) af[i] = *(const short8*)(ap + i * 512);
#pragma unroll
            for (int j = 0; j < 4; ++j) bfr[j] = *(const short8*)(bp + j * 512);
#pragma unroll
            for (int i = 0; i < 4; ++i)
#pragma unroll
                for (int j = 0; j < 4; ++j)
                    acc[i][j] = __builtin_amdgcn_mfma_f32_16x16x32_bf16(af[i], bfr[j], acc[i][j], 0, 0, 0);
        }
        ushort* dst = dsts[c];
#pragma unroll
        for (int j = 0; j < 4; ++j) {
            int col = wc * 64 + j * 16 + cl;
            float bv = bias[c * 128 + col];
            int h = col >> 5, dd = col & 31;
            ushort* hb = dst + ((size_t)(bidx * 4 + h) * NV + nbase) * DH + dd;
#pragma unroll
            for (int i = 0; i < 4; ++i) {
                int rbase = wr * 64 + i * 16 + q * 4;
#pragma unroll
                for (int r = 0; r < 4; ++r)
                    hb[(size_t)(rbase + r) * DH] = f2bf(acc[i][j][r] + bv);
            }
        }
    }
}

// ---------------- K3: V transpose -> vt [bh][32][1024] bf16 ----------------
__global__ __launch_bounds__(256) void k_vt(const ushort* __restrict__ vb, ushort* __restrict__ vt) {
    __shared__ ushort Ld[256 * 40];
    int bh = blockIdx.y, n0 = blockIdx.x * 256;
    int t = threadIdx.x;
    const ushort* src = vb + ((size_t)bh * NV + n0) * DH;
#pragma unroll
    for (int p = 0; p < 4; ++p) {
        int idx = p * 256 + t;
        int rowi = idx >> 2, ch = idx & 3;
        short8 u = *(const short8*)(src + idx * 8);
        *(short8*)(&Ld[rowi * 40 + ch * 8]) = u;
    }
    __syncthreads();
    int d = t >> 3, nc = (t & 7) * 32;
    ushort* dst = vt + ((size_t)bh * DH + d) * NV + n0 + nc;
#pragma unroll
    for (int p = 0; p < 4; ++p) {
        short8 u;
#pragma unroll
        for (int i = 0; i < 8; ++i) u[i] = (short)Ld[(nc + p * 8 + i) * 40 + d];
        *(short8*)(dst + p * 8) = u;
    }
}

// ---------------- K4: S = Q K^T / sqrt(dh) -> S f32 (d_out scratch) ----------------
__global__ __launch_bounds__(256) void k_qk(const ushort* __restrict__ qb, const ushort* __restrict__ kb,
                                            float* __restrict__ S) {
    __shared__ ushort As[128 * 32];
    __shared__ ushort Bs[128 * 32];
    int tile = blockIdx.x;
    int bh = blockIdx.y;
    int n0 = (tile >> 3) * 128, m0 = (tile & 7) * 128;
    int tid = threadIdx.x, lane = tid & 63, w = tid >> 6;
    int wr = w >> 1, wc = w & 1;
    const ushort* qt = qb + ((size_t)bh * NV + n0) * DH;
    const ushort* ktb = kb + ((size_t)bh * NV + m0) * DH;
#pragma unroll
    for (int p = 0; p < 2; ++p) {
        int ci = w * 2 + p;
        GLDS(qt + ci * 512 + lane * 8, As + ci * 512);
        GLDS(ktb + ci * 512 + lane * 8, Bs + ci * 512);
    }
    __syncthreads();
    int cl = lane & 15, q = lane >> 4;
    const ushort* ap = As + ((wr * 64 + cl) * 32 + q * 8);
    const ushort* bp = Bs + ((wc * 64 + cl) * 32 + q * 8);
    short8 af[4], bfr[4];
#pragma unroll
    for (int i = 0; i < 4; ++i) af[i] = *(const short8*)(ap + i * 512);
#pragma unroll
    for (int j = 0; j < 4; ++j) bfr[j] = *(const short8*)(bp + j * 512);
    f32x4 acc[4][4] = {};
#pragma unroll
    for (int i = 0; i < 4; ++i)
#pragma unroll
        for (int j = 0; j < 4; ++j)
            acc[i][j] = __builtin_amdgcn_mfma_f32_16x16x32_bf16(af[i], bfr[j], acc[i][j], 0, 0, 0);
    size_t sb = (size_t)bh * NV * NV;
#pragma unroll
    for (int i = 0; i < 4; ++i) {
        int rbase = n0 + wr * 64 + i * 16 + q * 4;
#pragma unroll
        for (int j = 0; j < 4; ++j) {
            int col = m0 + wc * 64 + j * 16 + cl;
#pragma unroll
            for (int r = 0; r < 4; ++r)
                S[sb + (size_t)(rbase + r) * NV + col] = acc[i][j][r] * 0.17677669529663687f;
        }
    }
}

// ---------------- K5: row softmax, P bf16 written in place ----------------
__global__ __launch_bounds__(256) void k_softmax(float* __restrict__ S) {
    __shared__ float red[4];
    int row = blockIdx.x, t = threadIdx.x, lane = t & 63;
    float* rp = S + (size_t)row * NV;
    float4 v = ((const float4*)rp)[t];
    float m = fmaxf(fmaxf(v.x, v.y), fmaxf(v.z, v.w));
#pragma unroll
    for (int off = 32; off; off >>= 1) m = fmaxf(m, __shfl_xor(m, off));
    if (lane == 0) red[t >> 6] = m;
    __syncthreads();
    m = fmaxf(fmaxf(red[0], red[1]), fmaxf(red[2], red[3]));
    __syncthreads();
    float e0 = __expf(v.x - m), e1 = __expf(v.y - m), e2 = __expf(v.z - m), e3 = __expf(v.w - m);
    float s4 = e0 + e1 + e2 + e3;
#pragma unroll
    for (int off = 32; off; off >>= 1) s4 += __shfl_xor(s4, off);
    if (lane == 0) red[t >> 6] = s4;
    __syncthreads();
    float inv = 1.0f / (red[0] + red[1] + red[2] + red[3]);
    ushort4 o;
    o.x = f2bf(e0 * inv); o.y = f2bf(e1 * inv); o.z = f2bf(e2 * inv); o.w = f2bf(e3 * inv);
    ((ushort4*)rp)[t] = o;
}

// ---------------- K6: O = P V -> obuf bf16 [8192][128] ----------------
__global__ __launch_bounds__(256) void k_pv(const float* __restrict__ Sf, const ushort* __restrict__ vt,
                                            ushort* __restrict__ obuf) {
    __shared__ ushort As[128 * 32];
    __shared__ ushort Bs[32 * 32];
    int n0 = blockIdx.x * 128, bh = blockIdx.y;
    int b = bh >> 2, h = bh & 3;
    int tid = threadIdx.x, lane = tid & 63, w = tid >> 6;
    const char* Sb = (const char*)Sf;
    const ushort* vtb = vt + (size_t)bh * DH * NV;
    f32x4 acc[2][2] = {};
    for (int kt = 0; kt < NV / 32; ++kt) {
        int k0 = kt * 32;
        __syncthreads();
#pragma unroll
        for (int p = 0; p < 2; ++p) {
            int ci = w * 2 + p;
            int rrow = ci * 16 + (lane >> 2);
            int kch = (lane & 3) * 8;
            const ushort* gp = (const ushort*)(Sb + (size_t)(bh * NV + n0 + rrow) * 4096) + k0 + kch;
            GLDS(gp, As + ci * 512);
        }
        if (tid < 128) {
            int d = tid >> 2, ch = tid & 3;
            short8 u = *(const short8*)(vtb + (size_t)d * NV + k0 + ch * 8);
            *(short8*)(&Bs[d * 32 + ch * 8]) = u;
        }
        __syncthreads();
        int cl = lane & 15, q = lane >> 4;
        const ushort* ap = As + ((w * 32 + cl) * 32 + q * 8);
        const ushort* bp = Bs + (cl * 32 + q * 8);
        short8 af[2], bfr[2];
#pragma unroll
        for (int i = 0; i < 2; ++i) af[i] = *(const short8*)(ap + i * 512);
#pragma unroll
        for (int j = 0; j < 2; ++j) bfr[j] = *(const short8*)(bp + j * 512);
#pragma unroll
        for (int i = 0; i < 2; ++i)
#pragma unroll
            for (int j = 0; j < 2; ++j)
                acc[i][j] = __builtin_amdgcn_mfma_f32_16x16x32_bf16(af[i], bfr[j], acc[i][j], 0, 0, 0);
    }
    int cl = lane & 15, q = lane >> 4;
#pragma unroll
    for (int i = 0; i < 2; ++i) {
        int rbase = n0 + w * 32 + i * 16 + q * 4;
#pragma unroll
        for (int j = 0; j < 2; ++j) {
            int d = j * 16 + cl;
#pragma unroll
            for (int r = 0; r < 4; ++r)
                obuf[((size_t)(b * NV + rbase + r)) * HH + h * DH + d] = f2bf(acc[i][j][r]);
        }
    }
}

// ---------------- K7: proj (MFMA) + residual -> eig ----------------
__global__ __launch_bounds__(256) void k_enc_proj(const ushort* __restrict__ obuf, const ushort* __restrict__ Wb,
                                                  const float* __restrict__ bias, float* __restrict__ eig) {
    __shared__ ushort As[16384];
    __shared__ ushort Bs[16384];
    int row0 = blockIdx.x * 128;
    int t = threadIdx.x, lane = t & 63, w = t >> 6;
    int wr = w >> 1, wc = w & 1;
#pragma unroll
    for (int p = 0; p < 8; ++p) {
        int ci = w * 8 + p;
        int kt = ci >> 3, rb = ci & 7;
        const ushort* gp = obuf + (size_t)(row0 + rb * 16 + (lane >> 2)) * HH + kt * 32 + (lane & 3) * 8;
        GLDS(gp, As + kt * 4096 + rb * 512);
        GLDS(Wb + WOFF_OUT + ci * 512 + lane * 8, Bs + ci * 512);
    }
    __syncthreads();
    int cl = lane & 15, q = lane >> 4;
    f32x4 acc[4][4] = {};
#pragma unroll
    for (int kt = 0; kt < 4; ++kt) {
        const ushort* ap = As + kt * 4096 + (wr * 64 + cl) * 32 + q * 8;
        const ushort* bp = Bs + kt * 4096 + (wc * 64 + cl) * 32 + q * 8;
        short8 af[4], bfr[4];
#pragma unroll
        for (int i = 0; i < 4; ++i) af[i] = *(const short8*)(ap + i * 512);
#pragma unroll
        for (int j = 0; j < 4; ++j) bfr[j] = *(const short8*)(bp + j * 512);
#pragma unroll
        for (int i = 0; i < 4; ++i)
#pragma unroll
            for (int j = 0; j < 4; ++j)
                acc[i][j] = __builtin_amdgcn_mfma_f32_16x16x32_bf16(af[i], bfr[j], acc[i][j], 0, 0, 0);
    }
#pragma unroll
    for (int j = 0; j < 4; ++j) {
        int col = wc * 64 + j * 16 + cl;
        float bv = bias[col];
#pragma unroll
        for (int i = 0; i < 4; ++i) {
            int rbase = wr * 64 + i * 16 + q * 4;
#pragma unroll
            for (int r = 0; r < 4; ++r) {
                size_t o = (size_t)(row0 + rbase + r) * HH + col;
                eig[o] += acc[i][j][r] + bv;
            }
        }
    }
}

// ---------------- K8: LN2 + FFN1 + gelu + FFN2 + residual (MFMA, fused) ----------------
__global__ __launch_bounds__(256) void k_enc_ffn(float* __restrict__ eig, const float* __restrict__ g,
                                                 const float* __restrict__ be, const ushort* __restrict__ Wb,
                                                 const float* __restrict__ b1, const float* __restrict__ b2) {
    __shared__ ushort As[16384];
    __shared__ ushort Bs[16384];
    int row0 = blockIdx.x * 128;
    int t = threadIdx.x, lane = t & 63, w = t >> 6;
    int wr = w >> 1, wc = w & 1;
    {
        int r = t >> 1, half = t & 1;
        const float4* rowp = (const float4*)(eig + (size_t)(row0 + r) * HH + half * 64);
        float4 v[16];
        float s = 0.f, s2 = 0.f;
#pragma unroll
        for (int i = 0; i < 16; ++i) {
            float4 a = rowp[i]; v[i] = a;
            s += a.x + a.y + a.z + a.w;
            s2 += a.x * a.x + a.y * a.y + a.z * a.z + a.w * a.w;
        }
        s += __shfl_xor(s, 1); s2 += __shfl_xor(s2, 1);
        float mean = s * 0.0078125f;
        float var = s2 * 0.0078125f - mean * mean;
        float rstd = rsqrtf(var + 1e-5f);
        const float4* g4 = (const float4*)(g + half * 64);
        const float4* b4 = (const float4*)(be + half * 64);
#pragma unroll
        for (int ch = 0; ch < 8; ++ch) {
            float4 a = v[2 * ch], bq = v[2 * ch + 1];
            float4 ga = g4[2 * ch], gb = g4[2 * ch + 1];
            float4 ba = b4[2 * ch], bb = b4[2 * ch + 1];
            short8 u;
            u[0] = (short)f2bf((a.x - mean) * rstd * ga.x + ba.x);
            u[1] = (short)f2bf((a.y - mean) * rstd * ga.y + ba.y);
            u[2] = (short)f2bf((a.z - mean) * rstd * ga.z + ba.z);
            u[3] = (short)f2bf((a.w - mean) * rstd * ga.w + ba.w);
            u[4] = (short)f2bf((bq.x - mean) * rstd * gb.x + bb.x);
            u[5] = (short)f2bf((bq.y - mean) * rstd * gb.y + bb.y);
            u[6] = (short)f2bf((bq.z - mean) * rstd * gb.z + bb.z);
            u[7] = (short)f2bf((bq.w - mean) * rstd * gb.w + bb.w);
            int k = half * 64 + ch * 8;
            *(short8*)(As + (k >> 5) * 4096 + r * 32 + (k & 31)) = u;
        }
    }
#pragma unroll
    for (int p = 0; p < 8; ++p) {
        int ci = w * 8 + p;
        GLDS(Wb + WOFF_F1 + ci * 512 + lane * 8, Bs + ci * 512);
    }
    __syncthreads();
    int cl = lane & 15, q = lane >> 4;
    f32x4 acc[4][4] = {};
#pragma unroll
    for (int kt = 0; kt < 4; ++kt) {
        const ushort* ap = As + kt * 4096 + (wr * 64 + cl) * 32 + q * 8;
        const ushort* bp = Bs + kt * 4096 + (wc * 64 + cl) * 32 + q * 8;
        short8 af[4], bfr[4];
#pragma unroll
        for (int i = 0; i < 4; ++i) af[i] = *(const short8*)(ap + i * 512);
#pragma unroll
        for (int j = 0; j < 4; ++j) bfr[j] = *(const short8*)(bp + j * 512);
#pragma unroll
        for (int i = 0; i < 4; ++i)
#pragma unroll
            for (int j = 0; j < 4; ++j)
                acc[i][j] = __builtin_amdgcn_mfma_f32_16x16x32_bf16(af[i], bfr[j], acc[i][j], 0, 0, 0);
    }
    __syncthreads();   // all waves done reading As/Bs
    // h = gelu(acc + b1) -> As (bf16, chunked); restage Bs = W2
#pragma unroll
    for (int j = 0; j < 4; ++j) {
        int col = wc * 64 + j * 16 + cl;
        float bv = b1[col];
        int koff = (col >> 5) * 4096 + (col & 31);
#pragma unroll
        for (int i = 0; i < 4; ++i) {
            int rbase = wr * 64 + i * 16 + q * 4;
#pragma unroll
            for (int r = 0; r < 4; ++r) {
                float a = acc[i][j][r] + bv;
                float ge = 0.5f * a * (1.0f + erff(a * 0.7071067811865475f));
                As[koff + (rbase + r) * 32] = f2bf(ge);
            }
        }
    }
#pragma unroll
    for (int p = 0; p < 8; ++p) {
        int ci = w * 8 + p;
        GLDS(Wb + WOFF_F2 + ci * 512 + lane * 8, Bs + ci * 512);
    }
    __syncthreads();
    f32x4 acc2[4][4] = {};
#pragma unroll
    for (int kt = 0; kt < 4; ++kt) {
        const ushort* ap = As + kt * 4096 + (wr * 64 + cl) * 32 + q * 8;
        const ushort* bp = Bs + kt * 4096 + (wc * 64 + cl) * 32 + q * 8;
        short8 af[4], bfr[4];
#pragma unroll
        for (int i = 0; i < 4; ++i) af[i] = *(const short8*)(ap + i * 512);
#pragma unroll
        for (int j = 0; j < 4; ++j) bfr[j] = *(const short8*)(bp + j * 512);
#pragma unroll
        for (int i = 0; i < 4; ++i)
#pragma unroll
            for (int j = 0; j < 4; ++j)
                acc2[i][j] = __builtin_amdgcn_mfma_f32_16x16x32_bf16(af[i], bfr[j], acc2[i][j], 0, 0, 0);
    }
#pragma unroll
    for (int j = 0; j < 4; ++j) {
        int col = wc * 64 + j * 16 + cl;
        float bv = b2[col];
#pragma unroll
        for (int i = 0; i < 4; ++i) {
            int rbase = wr * 64 + i * 16 + q * 4;
#pragma unroll
            for (int r = 0; r < 4; ++r) {
                size_t o = (size_t)(row0 + rbase + r) * HH + col;
                eig[o] += acc2[i][j][r] + bv;
            }
        }
    }
}

// ---------------- K9: mean pool over N ----------------
__global__ __launch_bounds__(1024) void k_meanpool(const float* __restrict__ eig, float* __restrict__ me) {
    __shared__ float part[8][HH];
    int b = blockIdx.x, t = threadIdx.x;
    int col = t & 127, grp = t >> 7;
    const float* p = eig + (size_t)b * NV * HH + (size_t)grp * 128 * HH + col;
    float s = 0.f;
    for (int n = 0; n < 128; ++n) s += p[(size_t)n * HH];
    part[grp][col] = s;
    __syncthreads();
    if (t < 128) {
        float a = 0.f;
#pragma unroll
        for (int g2 = 0; g2 < 8; ++g2) a += part[g2][t];
        me[b * HH + t] = a * (1.0f / NV);
    }
}

// ---------------- K10: decoders ----------------
__global__ void k_decoders(const float* __restrict__ me,
                           const float* __restrict__ dscW, const float* __restrict__ dscb,
                           const float* __restrict__ dwavW, const float* __restrict__ dwavb,
                           const float* __restrict__ dsclW, const float* __restrict__ dsclb,
                           float* __restrict__ cs, float* __restrict__ cw, float* __restrict__ csc) {
    __shared__ float m[HH];
    __shared__ float s1[NCOE], s2[NCOE];
    __shared__ float sums[2];
    int b = blockIdx.x, t = threadIdx.x;
    m[t] = me[b * HH + t];
    m[t + 64] = me[b * HH + t + 64];
    __syncthreads();
    if (t < NCOE) {
        float a = dscb[t], a2 = dwavb[t];
        const float* w1 = dscW + t * HH;
        const float* w2 = dwavW + t * HH;
        for (int j = 0; j < HH; ++j) { a += m[j] * w1[j]; a2 += m[j] * w2[j]; }
        s1[t] = 1.f / (1.f + __expf(-a));
        s2[t] = 1.f / (1.f + __expf(-a2));
    }
    if (t < NSC) {
        float a = dsclb[t];
        const float* wv = dsclW + t * HH;
        for (int j = 0; j < HH; ++j) a += m[j] * wv[j];
        csc[b * NSC + t] = 5.0f / (1.f + __expf(-a));
    }
    __syncthreads();
    if (t == 0) {
        float a = 0.f, bb = 0.f;
        for (int c = 0; c < NCOE; ++c) { a += s1[c]; bb += s2[c]; }
        sums[0] = a; sums[1] = bb;
    }
    __syncthreads();
    if (t < NCOE) {
        cs[b * NCOE + t] = s1[t] / (sums[0] + 1e-8f);
        cw[b * NCOE + t] = s2[t] / (sums[1] + 1e-8f);
    }
}

// ---------------- K11: Chebyshev -> fsaT [B,5,N] normalized (+ optional sqrt for symmetric GEMM) ----------------
__global__ void k_fsa(const float* __restrict__ ev, const float* __restrict__ cs,
                      const float* __restrict__ cw, const float* __restrict__ csc,
                      float* __restrict__ fsaT, float* __restrict__ fsqT) {
    __shared__ float lcs[NCOE], lcw[NCOE], lsc[NSC];
    int gid = blockIdx.x * 256 + threadIdx.x;
    int b = gid >> 10, n = gid & (NV - 1);
    int t = threadIdx.x;
    if (t < NCOE) { lcs[t] = cs[b * NCOE + t]; lcw[t] = cw[b * NCOE + t]; }
    if (t < NSC) lsc[t] = csc[b * NSC + t];
    __syncthreads();
    float e = ev[gid];
    float x = e - 1.0f;
    float te = 1.f, to = x;
    float a0 = lcs[0] * 0.5f * (1.f - to);
    for (int c = 1; c < NCOE; ++c) {
        te = 2.f * x * to - te;
        to = 2.f * x * te - to;
        a0 += lcs[c] * 0.5f * (1.f - to);
    }
    float aw[NSC];
#pragma unroll
    for (int s = 0; s < NSC; ++s) {
        float f = e * lsc[s];
        if (f > 2.0f) f = 0.0f;
        float y = f - 1.0f;
        float te2 = 1.f, to2 = y, a = 0.f;
        for (int c = 1; c < NCOE; ++c) {
            te2 = 2.f * y * to2 - te2;
            to2 = 2.f * y * te2 - to2;
            a += lcw[c] * 0.5f * (1.f - te2);
        }
        aw[s] = a;
    }
    float n2 = a0 * a0;
#pragma unroll
    for (int s = 0; s < NSC; ++s) n2 += aw[s] * aw[s];
    float inv = 1.f / (sqrtf(n2) + 1e-8f);
    float v0 = a0 * inv;
    fsaT[((size_t)b * 5 + 0) * NV + n] = v0;
    if (fsqT) fsqT[((size_t)b * 5 + 0) * NV + n] = sqrtf(fmaxf(v0, 0.f));
#pragma unroll
    for (int s = 0; s < NSC; ++s) {
        float vs = aw[s] * inv;
        fsaT[((size_t)b * 5 + 1 + s) * NV + n] = vs;
        if (fsqT) fsqT[((size_t)b * 5 + 1 + s) * NV + n] = sqrtf(fmaxf(vs, 0.f));
    }
}

// ---------------- K12: eigenvector f32 -> bf16 (fallback path only) ----------------
__global__ void k_tobf16(const float* __restrict__ in, ushort* __restrict__ outp) {
    int i = blockIdx.x * 256 + threadIdx.x;
    const float4* p = (const float4*)in + (size_t)i * 2;
    float4 a = p[0], bq = p[1];
    uint4 r;
    r.x = (uint)f2bf(a.x) | ((uint)f2bf(a.y) << 16);
    r.y = (uint)f2bf(a.z) | ((uint)f2bf(a.w) << 16);
    r.z = (uint)f2bf(bq.x) | ((uint)f2bf(bq.y) << 16);
    r.w = (uint)f2bf(bq.z) | ((uint)f2bf(bq.w) << 16);
    ((uint4*)outp)[i] = r;
}

// ---------------- K12b: prescale Asc[b][s][n][k] = bf16(V[n,k] * sqrt(fsa[b,s,k])) ----------------
// Global layout is pre-swizzled: granule g (8 consecutive k within each 32-k tile) is stored at
// g ^ ((n>>2)&3) so that linear global_load_lds yields a bank-balanced LDS image (rule #21:
// swizzle on SOURCE + same swizzle on READ, LDS dest stays linear).
__global__ __launch_bounds__(256) void k_prescale(const float* __restrict__ evec, const float* __restrict__ fsq,
                                                  ushort* __restrict__ Asc) {
    int gid = blockIdx.x * 256 + threadIdx.x;     // 8*1024*128 threads: (b, n, granule)
    int gk = gid & 127;
    int n = (gid >> 7) & (NV - 1);
    int b = gid >> 17;
    const float4* vp = (const float4*)(evec + ((size_t)b * NV + n) * NV + gk * 8);
    float4 a = vp[0], c = vp[1];
    int gsw = (gk & ~3) | ((gk ^ (n >> 2)) & 3);
    size_t dstbase = ((size_t)(b * 5) * NV + n) * NV + (size_t)gsw * 8;
#pragma unroll
    for (int s = 0; s < 5; ++s) {
        const float* fp = fsq + (size_t)(b * 5 + s) * NV + gk * 8;
        float4 f0 = *(const float4*)fp, f1 = *(const float4*)(fp + 4);
        uint4 r;
        r.x = (uint)f2bf(a.x * f0.x) | ((uint)f2bf(a.y * f0.y) << 16);
        r.y = (uint)f2bf(a.z * f0.z) | ((uint)f2bf(a.w * f0.w) << 16);
        r.z = (uint)f2bf(c.x * f1.x) | ((uint)f2bf(c.y * f1.y) << 16);
        r.w = (uint)f2bf(c.z * f1.z) | ((uint)f2bf(c.w * f1.w) << 16);
        *(uint4*)(Asc + dstbase + (size_t)s * NV * NV) = r;
    }
}

// ---------------- K13b: symmetric filters GEMM: C = Asc Asc^T, upper-triangular tiles only ----------------
// 2-phase software pipeline (T3 minimum recipe): double-buffered LDS, prefetch kt+1 issued
// before compute of kt, ONE barrier per K-step. Writes only the upper tile (mirror produced
// by k_norm_sym); cn via col-sum atomics (all tiles) + row-sum atomics (off-diag tiles).
__global__ __launch_bounds__(256) void k_gemm_sym(const ushort* __restrict__ Asc,
                                                  float* __restrict__ out,
                                                  float* __restrict__ cn) {
    __shared__ ushort As[2][4096];
    __shared__ ushort Bs[2][4096];
    // bijective XCD swizzle over 1440 blocks (1440 % 8 == 0): each XCD gets 180 consecutive
    // work ids = 5 complete (b,s) groups -> (b,s)'s 2MB operand stays in one XCD L2.
    int lin = blockIdx.x;
    int wg = (lin & 7) * 180 + (lin >> 3);
    int bs = wg / 36, p = wg % 36;
    int b = bs / 5, s = bs % 5;
    int ti = 0, rem = p;
    while (rem >= 8 - ti) { rem -= 8 - ti; ++ti; }
    int tj = ti + rem;
    int n0 = ti * 128, m0 = tj * 128;
    int tid = threadIdx.x, lane = tid & 63, w = tid >> 6;
    int wr = w >> 1, wc = w & 1;
    const ushort* Abase = Asc + (size_t)(b * 5 + s) * NV * NV;
    const ushort* an = Abase + (size_t)n0 * NV;
    const ushort* am = Abase + (size_t)m0 * NV;
    int rrow0 = lane >> 2;              // 0..15
    int kch = (lane & 3) * 8;
    int cl = lane & 15, q = lane >> 4;
    int qx = (q ^ (cl >> 2)) & 3;       // un-swizzle on read (matches k_prescale's granule XOR)
    int fo = cl * 32 + qx * 8;

    auto STAGE = [&](int nb, int k0) {
#pragma unroll
        for (int p2 = 0; p2 < 2; ++p2) {
            int ci = w * 2 + p2;
            int rr = ci * 16 + rrow0;
            GLDS(an + (size_t)rr * NV + k0 + kch, &As[nb][ci * 512]);
            GLDS(am + (size_t)rr * NV + k0 + kch, &Bs[nb][ci * 512]);
        }
    };

    f32x4 acc[4][4] = {};
    STAGE(0, 0);
    __syncthreads();                     // vmcnt(0) drain: buf0 ready
    for (int kt = 0; kt < 31; ++kt) {
        int cur = kt & 1;
        STAGE(cur ^ 1, (kt + 1) * 32);   // prefetch next K-step (async, drains at loop-end barrier)
        short8 af[4], bfr[4];
#pragma unroll
        for (int i = 0; i < 4; ++i) af[i] = *(const short8*)(&As[cur][(wr * 4 + i) * 512 + fo]);
#pragma unroll
        for (int j = 0; j < 4; ++j) bfr[j] = *(const short8*)(&Bs[cur][(wc * 4 + j) * 512 + fo]);
#pragma unroll
        for (int i = 0; i < 4; ++i)
#pragma unroll
            for (int j = 0; j < 4; ++j)
                acc[i][j] = __builtin_amdgcn_mfma_f32_16x16x32_bf16(af[i], bfr[j], acc[i][j], 0, 0, 0);
        __syncthreads();                 // next buf staged + all waves done reading cur
    }
    {   // epilogue: kt = 31 from buffer 1, no prefetch
        short8 af[4], bfr[4];
#pragma unroll
        for (int i = 0; i < 4; ++i) af[i] = *(const short8*)(&As[1][(wr * 4 + i) * 512 + fo]);
#pragma unroll
        for (int j = 0; j < 4; ++j) bfr[j] = *(const short8*)(&Bs[1][(wc * 4 + j) * 512 + fo]);
#pragma unroll
        for (int i = 0; i < 4; ++i)
#pragma unroll
            for (int j = 0; j < 4; ++j)
                acc[i][j] = __builtin_amdgcn_mfma_f32_16x16x32_bf16(af[i], bfr[j], acc[i][j], 0, 0, 0);
    }
    size_t ob = (size_t)(s * BB + b) * NV * NV;
    float* cnb = cn + (size_t)(s * BB + b) * NV;
    float colss[4] = {0.f, 0.f, 0.f, 0.f};
    float rowss[4][4];
#pragma unroll
    for (int i = 0; i < 4; ++i)
#pragma unroll
        for (int r = 0; r < 4; ++r) rowss[i][r] = 0.f;
#pragma unroll
    for (int i = 0; i < 4; ++i) {
        int rbase = n0 + wr * 64 + i * 16 + q * 4;
#pragma unroll
        for (int j = 0; j < 4; ++j) {
            int col = m0 + wc * 64 + j * 16 + cl;
#pragma unroll
            for (int r = 0; r < 4; ++r) {
                float v = acc[i][j][r];
                out[ob + (size_t)(rbase + r) * NV + col] = v;
                colss[j] += v * v;
                rowss[i][r] += v * v;
            }
        }
    }
    // column sums of this tile -> cn[m-range]
#pragma unroll
    for (int j = 0; j < 4; ++j) {
        float v = colss[j];
        v += __shfl_xor(v, 16);
        v += __shfl_xor(v, 32);
        if (q == 0) atomicAdd(cnb + (m0 + wc * 64 + j * 16 + cl), v);
    }
    // row sums (= column sums of the mirror tile) -> cn[n-range], off-diag only
    if (ti != tj) {
#pragma unroll
        for (int i = 0; i < 4; ++i)
#pragma unroll
            for (int r = 0; r < 4; ++r) {
                float v = rowss[i][r];
                v += __shfl_xor(v, 1); v += __shfl_xor(v, 2);
                v += __shfl_xor(v, 4); v += __shfl_xor(v, 8);
                if (cl == 0) atomicAdd(cnb + (n0 + wr * 64 + i * 16 + q * 4 + r), v);
            }
    }
}

// ---------------- K13: filters GEMM (fallback path: on-the-fly scaling) ----------------
__global__ __launch_bounds__(256) void k_gemm(const ushort* __restrict__ Vb,
                                              const float* __restrict__ fsaT,
                                              float* __restrict__ out,
                                              float* __restrict__ cn) {
    __shared__ ushort As[128 * 32];
    __shared__ ushort Bs[128 * 32];
    int tile = blockIdx.x;
    int bsid = blockIdx.y;
    int b = bsid / 5, s = bsid % 5;
    int n0 = (tile >> 3) * 128, m0 = (tile & 7) * 128;
    int tid = threadIdx.x, lane = tid & 63, w = tid >> 6;
    int wr = w >> 1, wc = w & 1;
    const ushort* Vbase = Vb + (size_t)b * NV * NV;
    const float* fs = fsaT + ((size_t)b * 5 + s) * NV;
    f32x4 acc[4][4] = {};

    for (int kt = 0; kt < NV / 32; ++kt) {
        int k0 = kt * 32;
        __syncthreads();
#pragma unroll
        for (int p = 0; p < 2; ++p) {
            int ci = w * 2 + p;
            int rrow = ci * 16 + (lane >> 2);
            int kch = (lane & 3) * 8;
            const ushort* gp = Vbase + (size_t)(m0 + rrow) * NV + k0 + kch;
            GLDS(gp, Bs + ci * 512);
        }
#pragma unroll
        for (int p = 0; p < 2; ++p) {
            int idx = p * 256 + tid;
            int rrow = idx >> 2;
            int kch = (idx & 3) * 8;
            const ushort* gp = Vbase + (size_t)(n0 + rrow) * NV + k0 + kch;
            uint4 raw = *(const uint4*)gp;
            const float4* fp = (const float4*)(fs + k0 + kch);
            float4 f0 = fp[0], f1 = fp[1];
            float v0 = __uint_as_float(raw.x << 16) * f0.x;
            float v1 = __uint_as_float(raw.x & 0xffff0000u) * f0.y;
            float v2 = __uint_as_float(raw.y << 16) * f0.z;
            float v3 = __uint_as_float(raw.y & 0xffff0000u) * f0.w;
            float v4 = __uint_as_float(raw.z << 16) * f1.x;
            float v5 = __uint_as_float(raw.z & 0xffff0000u) * f1.y;
            float v6 = __uint_as_float(raw.w << 16) * f1.z;
            float v7 = __uint_as_float(raw.w & 0xffff0000u) * f1.w;
            uint4 rr;
            rr.x = (uint)f2bf(v0) | ((uint)f2bf(v1) << 16);
            rr.y = (uint)f2bf(v2) | ((uint)f2bf(v3) << 16);
            rr.z = (uint)f2bf(v4) | ((uint)f2bf(v5) << 16);
            rr.w = (uint)f2bf(v6) | ((uint)f2bf(v7) << 16);
            *(uint4*)(As + rrow * 32 + kch) = rr;
        }
        __syncthreads();
        int cl = lane & 15, q = lane >> 4;
        const ushort* ap = As + ((wr * 64 + cl) * 32 + q * 8);
        const ushort* bp = Bs + ((wc * 64 + cl) * 32 + q * 8);
        short8 af[4], bfr[4];
#pragma unroll
        for (int i = 0; i < 4; ++i) af[i] = *(const short8*)(ap + i * 512);
#pragma unroll
        for (int j = 0; j < 4; ++j) bfr[j] = *(const short8*)(bp + j * 512);
#pragma unroll
        for (int i = 0; i < 4; ++i)
#pragma unroll
            for (int j = 0; j < 4; ++j)
                acc[i][j] = __builtin_amdgcn_mfma_f32_16x16x32_bf16(af[i], bfr[j], acc[i][j], 0, 0, 0);
    }
    int cl = lane & 15, q = lane >> 4;
    size_t ob = (size_t)(s * BB + b) * NV * NV;
    float colss[4] = {0.f, 0.f, 0.f, 0.f};
#pragma unroll
    for (int i = 0; i < 4; ++i) {
        int rbase = n0 + wr * 64 + i * 16 + q * 4;
#pragma unroll
        for (int j = 0; j < 4; ++j) {
            int col = m0 + wc * 64 + j * 16 + cl;
#pragma unroll
            for (int r = 0; r < 4; ++r) {
                float v = acc[i][j][r];
                out[ob + (size_t)(rbase + r) * NV + col] = v;
                colss[j] += v * v;
            }
        }
    }
    float* cnb = cn + (size_t)(s * BB + b) * NV;
#pragma unroll
    for (int j = 0; j < 4; ++j) {
        float v = colss[j];
        v += __shfl_xor(v, 16);
        v += __shfl_xor(v, 32);
        if (q == 0) atomicAdd(cnb + (m0 + wc * 64 + j * 16 + cl), v);
    }
}

// ---------------- K14b: tile normalization + mirror write (symmetric path) ----------------
// Block owns upper tile (ti<=tj): reads it ONCE, writes it back normalized (cols m0..),
// and (ti<tj) writes the mirror tile (rows m0.., cols n0..) normalized, via LDS transpose.
__global__ __launch_bounds__(256) void k_norm_sym(float* __restrict__ out, const float* __restrict__ cn) {
    __shared__ float L[128][68];
    int ti = blockIdx.x >> 3, tj = blockIdx.x & 7;
    if (ti > tj) return;
    int bs = blockIdx.y;
    int n0 = ti * 128, m0 = tj * 128;
    size_t ob = (size_t)bs * NV * NV;
    const float* cnb = cn + (size_t)bs * NV;
    int t = threadIdx.x;
#pragma unroll 1
    for (int ch = 0; ch < 2; ++ch) {
        if (ch) __syncthreads();      // ch0 mirror reads of L done before ch1 restage
        // read 64x128 chunk (rows n0+ch*64..), normalize in place, stage raw values transposed
#pragma unroll
        for (int p = 0; p < 8; ++p) {
            int idx = p * 256 + t;
            int r = idx >> 5;                 // 0..63
            int c4 = (idx & 31) * 4;          // 0..124
            size_t o = ob + (size_t)(n0 + ch * 64 + r) * NV + m0 + c4;
            float4 v = *(float4*)(out + o);
            float4 sm = *(const float4*)(cnb + m0 + c4);
            float4 wv;
            wv.x = v.x * (1.f / fmaxf(sqrtf(sm.x), 1e-12f));
            wv.y = v.y * (1.f / fmaxf(sqrtf(sm.y), 1e-12f));
            wv.z = v.z * (1.f / fmaxf(sqrtf(sm.z), 1e-12f));
            wv.w = v.w * (1.f / fmaxf(sqrtf(sm.w), 1e-12f));
            *(float4*)(out + o) = wv;
            if (ti != tj) {
                L[c4 + 0][r] = v.x; L[c4 + 1][r] = v.y;
                L[c4 + 2][r] = v.z; L[c4 + 3][r] = v.w;
            }
        }
        if (ti != tj) {
            __syncthreads();
            // mirror: out[m0+mr][n0+ch*64+j] = C[m0+mr][n0+..+j] / cn[n0+..+j] = L[mr][j] * inv
#pragma unroll
            for (int p = 0; p < 8; ++p) {
                int idx = p * 256 + t;
                int mr = idx >> 4;            // 0..127
                int j4 = (idx & 15) * 4;      // 0..60
                float4 sn = *(const float4*)(cnb + n0 + ch * 64 + j4);
                float4 wv;
                wv.x = L[mr][j4 + 0] * (1.f / fmaxf(sqrtf(sn.x), 1e-12f));
                wv.y = L[mr][j4 + 1] * (1.f / fmaxf(sqrtf(sn.y), 1e-12f));
                wv.z = L[mr][j4 + 2] * (1.f / fmaxf(sqrtf(sn.z), 1e-12f));
                wv.w = L[mr][j4 + 3] * (1.f / fmaxf(sqrtf(sn.w), 1e-12f));
                *(float4*)(out + ob + (size_t)(m0 + mr) * NV + n0 + ch * 64 + j4) = wv;
            }
        }
    }
}

// ---------------- K14: column normalization (fallback path) ----------------
__global__ void k_norm(float* __restrict__ out, const float* __restrict__ cn) {
    int bid = blockIdx.x;
    int bs = bid >> 10, n = bid & (NV - 1);
    int m4 = threadIdx.x * 4;
    float4 ssv = *(const float4*)(cn + (size_t)bs * NV + m4);
    float4* p = (float4*)(out + ((size_t)bs * NV + n) * NV + m4);
    float4 v = *p;
    v.x *= 1.f / fmaxf(sqrtf(ssv.x), 1e-12f);
    v.y *= 1.f / fmaxf(sqrtf(ssv.y), 1e-12f);
    v.z *= 1.f / fmaxf(sqrtf(ssv.z), 1e-12f);
    v.w *= 1.f / fmaxf(sqrtf(ssv.w), 1e-12f);
    *p = v;
}

extern "C" void kernel_launch(void* const* d_in, const int* in_sizes, int n_in,
                              void* d_out, int out_size, void* d_ws, size_t ws_size,
                              hipStream_t stream) {
    const float* eigenvalue = (const float*)d_in[0];
    const float* eigenvector = (const float*)d_in[1];
    const float* eigw_W = (const float*)d_in[2];
    const float* eigw_b = (const float*)d_in[3];
    const float* ln1_g = (const float*)d_in[4];
    const float* ln1_b = (const float*)d_in[5];
    const float* qkv_W = (const float*)d_in[6];
    const float* qkv_b = (const float*)d_in[7];
    const float* out_W = (const float*)d_in[8];
    const float* out_b = (const float*)d_in[9];
    const float* ln2_g = (const float*)d_in[10];
    const float* ln2_b = (const float*)d_in[11];
    const float* ffn1_W = (const float*)d_in[12];
    const float* ffn1_b = (const float*)d_in[13];
    const float* ffn2_W = (const float*)d_in[14];
    const float* ffn2_b = (const float*)d_in[15];
    const float* dsc_W = (const float*)d_in[16];
    const float* dsc_b = (const float*)d_in[17];
    const float* dwav_W = (const float*)d_in[18];
    const float* dwav_b = (const float*)d_in[19];
    const float* dscl_W = (const float*)d_in[20];
    const float* dscl_b = (const float*)d_in[21];

    char* w = (char*)d_ws;
    float* eig  = (float*)(w + 0);             // 4 MB
    float* me   = (float*)(w + 4194304);       // 4 KB
    float* cs   = (float*)(w + 4198400);       // 2 KB
    float* cw   = (float*)(w + 4200448);       // 2 KB
    float* csc  = (float*)(w + 4202496);       // 1 KB
    float* fsaT = (float*)(w + 4203520);       // 160 KB
    float* cn   = (float*)(w + 4367360);       // 160 KB
    ushort* qb  = (ushort*)(w + 4531200);      // 2 MB
    ushort* kb  = (ushort*)(w + 6628352);      // 2 MB
    ushort* vb  = (ushort*)(w + 8725504);      // 2 MB
    ushort* vt  = (ushort*)(w + 10822656);     // 2 MB
    ushort* obuf = (ushort*)(w + 12919808);    // 2 MB
    ushort* Wb  = (ushort*)(w + 15016960);     // 224 KB
    ushort* Vb  = (ushort*)(w + 15246336);     // 16 MB -> end 32,023,552

    // symmetric-GEMM path extras (only touched when ws_size admits them)
    bool big = ws_size >= (size_t)117440512;   // 32MiB block + fsqT + 84MB Asc
    float* fsqT = big ? (float*)(w + 32023552) : nullptr;   // 160 KB
    ushort* Asc = (ushort*)(w + 33554432);                  // 84 MB (40 x 1024 x 1024 bf16)

    float* outp = (float*)d_out;
    float* S = (float*)d_out;   // scratch region, overwritten later by the filters GEMM

    hipMemsetAsync(cn, 0, 40 * NV * sizeof(float), stream);

    k_wcvt<<<dim3(WB_ELEMS / 256), dim3(256), 0, stream>>>(eigw_W, qkv_W, out_W, ffn1_W, ffn2_W, Wb);
    k_enc_sine<<<dim3(64), dim3(256), 0, stream>>>(eigenvalue, Wb, eigw_W, eigw_b, eig);
    k_enc_qkv<<<dim3(64), dim3(256), 0, stream>>>(eig, ln1_g, ln1_b, Wb, qkv_b, qb, kb, vb);
    k_vt<<<dim3(4, 32), dim3(256), 0, stream>>>(vb, vt);
    k_qk<<<dim3(64, 32), dim3(256), 0, stream>>>(qb, kb, S);
    k_softmax<<<dim3(32 * NV), dim3(256), 0, stream>>>(S);
    k_pv<<<dim3(8, 32), dim3(256), 0, stream>>>(S, vt, obuf);
    k_enc_proj<<<dim3(64), dim3(256), 0, stream>>>(obuf, Wb, out_b, eig);
    k_enc_ffn<<<dim3(64), dim3(256), 0, stream>>>(eig, ln2_g, ln2_b, Wb, ffn1_b, ffn2_b);
    k_meanpool<<<dim3(BB), dim3(1024), 0, stream>>>(eig, me);
    k_decoders<<<dim3(BB), dim3(64), 0, stream>>>(me, dsc_W, dsc_b, dwav_W, dwav_b, dscl_W, dscl_b, cs, cw, csc);
    k_fsa<<<dim3(BB * NV / 256), dim3(256), 0, stream>>>(eigenvalue, cs, cw, csc, fsaT, fsqT);
    if (big) {
        // filters = (V sqrt(F)) (V sqrt(F))^T : prescale once, pipelined symmetric GEMM on
        // 36/64 tile-pairs (upper only), then normalize + mirror in one pass.
        k_prescale<<<dim3(BB * NV * 128 / 256), dim3(256), 0, stream>>>(eigenvector, fsqT, Asc);
        k_gemm_sym<<<dim3(36 * 40), dim3(256), 0, stream>>>(Asc, outp, cn);
        k_norm_sym<<<dim3(64, 40), dim3(256), 0, stream>>>(outp, cn);
    } else {
        k_tobf16<<<dim3(BB * NV * NV / (8 * 256)), dim3(256), 0, stream>>>(eigenvector, Vb);
        k_gemm<<<dim3(64, 40), dim3(256), 0, stream>>>(Vb, fsaT, outp, cn);
        k_norm<<<dim3(40 * NV), dim3(256), 0, stream>>>(outp, cn);
    }
}

// Round 6
// 489.806 us; speedup vs baseline: 1.0736x; 1.0736x over previous
//
#include <hip/hip_runtime.h>
#include <hip/hip_bf16.h>
#include <cstdint>

#define BB 8
#define NV 1024
#define HH 128
#define DH 32
#define NCOE 50
#define NSC 4

// Wb segment offsets (elements)
#define WOFF_EIG 0
#define WOFF_QKV 16384
#define WOFF_OUT 65536
#define WOFF_F1  81920
#define WOFF_F2  98304
#define WB_ELEMS 114688

typedef __attribute__((ext_vector_type(8))) short short8;
typedef __attribute__((ext_vector_type(4))) float f32x4;

__device__ __forceinline__ ushort f2bf(float f) {
    uint32_t x = __float_as_uint(f);
    uint32_t r = x + 0x7FFFu + ((x >> 16) & 1u);
    return (ushort)(r >> 16);
}

#define GLDS(gp, lp) __builtin_amdgcn_global_load_lds((const __attribute__((address_space(1))) void*)(gp), (__attribute__((address_space(3))) void*)(lp), 16, 0, 0)

// ---------------- K0: weight convert f32 -> bf16, LDS-chunked layout [kt][r][32] ----------------
__global__ void k_wcvt(const float* __restrict__ eigw_W, const float* __restrict__ qkv_W,
                       const float* __restrict__ out_W, const float* __restrict__ f1W,
                       const float* __restrict__ f2W, ushort* __restrict__ Wb) {
    int idx = blockIdx.x * 256 + threadIdx.x;
    float v; int dst;
    if (idx < 16384) {                 // eigw cols 1..128
        int r = idx >> 7, k = idx & 127;
        v = eigw_W[r * 129 + 1 + k];
        dst = WOFF_EIG + (k >> 5) * 4096 + r * 32 + (k & 31);
    } else if (idx < 65536) {          // qkv_W, 3 chunks of 128 rows
        int l = idx - 16384; int c = l >> 14, rem = l & 16383;
        int r = rem >> 7, k = rem & 127;
        v = qkv_W[(size_t)(c * 128 + r) * 128 + k];
        dst = WOFF_QKV + c * 16384 + (k >> 5) * 4096 + r * 32 + (k & 31);
    } else if (idx < 81920) {          // out_W
        int l = idx - 65536; int r = l >> 7, k = l & 127;
        v = out_W[r * 128 + k];
        dst = WOFF_OUT + (k >> 5) * 4096 + r * 32 + (k & 31);
    } else if (idx < 98304) {          // ffn1_W
        int l = idx - 81920; int r = l >> 7, k = l & 127;
        v = f1W[r * 128 + k];
        dst = WOFF_F1 + (k >> 5) * 4096 + r * 32 + (k & 31);
    } else {                           // ffn2_W
        int l = idx - 98304; int r = l >> 7, k = l & 127;
        v = f2W[r * 128 + k];
        dst = WOFF_F2 + (k >> 5) * 4096 + r * 32 + (k & 31);
    }
    Wb[dst] = f2bf(v);
}

// ---------------- K1: sine encoding + eigw linear (MFMA) -> eig f32 [8192][128] ----------------
__global__ __launch_bounds__(256) void k_enc_sine(const float* __restrict__ ev, const ushort* __restrict__ Wb,
                                                  const float* __restrict__ eigw_W, const float* __restrict__ eigw_b,
                                                  float* __restrict__ eig) {
    __shared__ ushort As[16384];
    __shared__ ushort Bs[16384];
    int row0 = blockIdx.x * 128;
    int t = threadIdx.x, lane = t & 63, w = t >> 6;
    int wr = w >> 1, wc = w & 1;
#pragma unroll
    for (int p = 0; p < 8; ++p) {
        int ci = w * 8 + p;
        GLDS(Wb + WOFF_EIG + ci * 512 + lane * 8, Bs + ci * 512);
    }
    {
        int r = t >> 1, half = t & 1;
        float e = ev[row0 + r] * 100.0f;
#pragma unroll
        for (int ch = 0; ch < 8; ++ch) {
            short8 u;
#pragma unroll
            for (int l = 0; l < 8; ++l) {
                int j = ch * 8 + l;
                float div = expf((float)(2 * j) * -0.07195578415606394f);
                float pe = e * div;
                u[l] = (short)f2bf(half ? cosf(pe) : sinf(pe));
            }
            int k = half * 64 + ch * 8;
            *(short8*)(As + (k >> 5) * 4096 + r * 32 + (k & 31)) = u;
        }
    }
    __syncthreads();
    int cl = lane & 15, q = lane >> 4;
    f32x4 acc[4][4] = {};
#pragma unroll
    for (int kt = 0; kt < 4; ++kt) {
        const ushort* ap = As + kt * 4096 + (wr * 64 + cl) * 32 + q * 8;
        const ushort* bp = Bs + kt * 4096 + (wc * 64 + cl) * 32 + q * 8;
        short8 af[4], bfr[4];
#pragma unroll
        for (int i = 0; i < 4; ++i) af[i] = *(const short8*)(ap + i * 512);
#pragma unroll
        for (int j = 0; j < 4; ++j) bfr[j] = *(const short8*)(bp + j * 512);
#pragma unroll
        for (int i = 0; i < 4; ++i)
#pragma unroll
            for (int j = 0; j < 4; ++j)
                acc[i][j] = __builtin_amdgcn_mfma_f32_16x16x32_bf16(af[i], bfr[j], acc[i][j], 0, 0, 0);
    }
#pragma unroll
    for (int i = 0; i < 4; ++i) {
        int rbase = wr * 64 + i * 16 + q * 4;
        float er[4];
#pragma unroll
        for (int r = 0; r < 4; ++r) er[r] = ev[row0 + rbase + r];
#pragma unroll
        for (int j = 0; j < 4; ++j) {
            int col = wc * 64 + j * 16 + cl;
            float w0 = eigw_W[col * 129];
            float bv = eigw_b[col];
#pragma unroll
            for (int r = 0; r < 4; ++r)
                eig[(size_t)(row0 + rbase + r) * HH + col] = acc[i][j][r] + er[r] * w0 + bv;
        }
    }
}

// ---------------- K2: LN1 + QKV (MFMA) -> q/k/v bf16 head-major [bh][n][32] ----------------
__global__ __launch_bounds__(256) void k_enc_qkv(const float* __restrict__ eig, const float* __restrict__ g,
                                                 const float* __restrict__ be, const ushort* __restrict__ Wb,
                                                 const float* __restrict__ bias,
                                                 ushort* __restrict__ qb, ushort* __restrict__ kb, ushort* __restrict__ vb) {
    __shared__ ushort As[16384];
    __shared__ ushort Bs[16384];
    int row0 = blockIdx.x * 128;
    int t = threadIdx.x, lane = t & 63, w = t >> 6;
    int wr = w >> 1, wc = w & 1;
    {
        int r = t >> 1, half = t & 1;
        const float4* rowp = (const float4*)(eig + (size_t)(row0 + r) * HH + half * 64);
        float4 v[16];
        float s = 0.f, s2 = 0.f;
#pragma unroll
        for (int i = 0; i < 16; ++i) {
            float4 a = rowp[i]; v[i] = a;
            s += a.x + a.y + a.z + a.w;
            s2 += a.x * a.x + a.y * a.y + a.z * a.z + a.w * a.w;
        }
        s += __shfl_xor(s, 1); s2 += __shfl_xor(s2, 1);
        float mean = s * 0.0078125f;
        float var = s2 * 0.0078125f - mean * mean;
        float rstd = rsqrtf(var + 1e-5f);
        const float4* g4 = (const float4*)(g + half * 64);
        const float4* b4 = (const float4*)(be + half * 64);
#pragma unroll
        for (int ch = 0; ch < 8; ++ch) {
            float4 a = v[2 * ch], b2 = v[2 * ch + 1];
            float4 ga = g4[2 * ch], gb = g4[2 * ch + 1];
            float4 ba = b4[2 * ch], bb = b4[2 * ch + 1];
            short8 u;
            u[0] = (short)f2bf((a.x - mean) * rstd * ga.x + ba.x);
            u[1] = (short)f2bf((a.y - mean) * rstd * ga.y + ba.y);
            u[2] = (short)f2bf((a.z - mean) * rstd * ga.z + ba.z);
            u[3] = (short)f2bf((a.w - mean) * rstd * ga.w + ba.w);
            u[4] = (short)f2bf((b2.x - mean) * rstd * gb.x + bb.x);
            u[5] = (short)f2bf((b2.y - mean) * rstd * gb.y + bb.y);
            u[6] = (short)f2bf((b2.z - mean) * rstd * gb.z + bb.z);
            u[7] = (short)f2bf((b2.w - mean) * rstd * gb.w + bb.w);
            int k = half * 64 + ch * 8;
            *(short8*)(As + (k >> 5) * 4096 + r * 32 + (k & 31)) = u;
        }
    }
    int cl = lane & 15, q = lane >> 4;
    int bidx = row0 >> 10, nbase = row0 & (NV - 1);
    ushort* dsts[3] = {qb, kb, vb};
#pragma unroll 1
    for (int c = 0; c < 3; ++c) {
        __syncthreads();
#pragma unroll
        for (int p = 0; p < 8; ++p) {
            int ci = w * 8 + p;
            GLDS(Wb + WOFF_QKV + c * 16384 + ci * 512 + lane * 8, Bs + ci * 512);
        }
        __syncthreads();
        f32x4 acc[4][4] = {};
#pragma unroll
        for (int kt = 0; kt < 4; ++kt) {
            const ushort* ap = As + kt * 4096 + (wr * 64 + cl) * 32 + q * 8;
            const ushort* bp = Bs + kt * 4096 + (wc * 64 + cl) * 32 + q * 8;
            short8 af[4], bfr[4];
#pragma unroll
            for (int i = 0; i < 4; ++i) af[i] = *(const short8*)(ap + i * 512);
#pragma unroll
            for (int j = 0; j < 4; ++j) bfr[j] = *(const short8*)(bp + j * 512);
#pragma unroll
            for (int i = 0; i < 4; ++i)
#pragma unroll
                for (int j = 0; j < 4; ++j)
                    acc[i][j] = __builtin_amdgcn_mfma_f32_16x16x32_bf16(af[i], bfr[j], acc[i][j], 0, 0, 0);
        }
        ushort* dst = dsts[c];
#pragma unroll
        for (int j = 0; j < 4; ++j) {
            int col = wc * 64 + j * 16 + cl;
            float bv = bias[c * 128 + col];
            int h = col >> 5, dd = col & 31;
            ushort* hb = dst + ((size_t)(bidx * 4 + h) * NV + nbase) * DH + dd;
#pragma unroll
            for (int i = 0; i < 4; ++i) {
                int rbase = wr * 64 + i * 16 + q * 4;
#pragma unroll
                for (int r = 0; r < 4; ++r)
                    hb[(size_t)(rbase + r) * DH] = f2bf(acc[i][j][r] + bv);
            }
        }
    }
}

// ---------------- K3: V transpose -> vt [bh][32][1024] bf16 ----------------
__global__ __launch_bounds__(256) void k_vt(const ushort* __restrict__ vb, ushort* __restrict__ vt) {
    __shared__ ushort Ld[256 * 40];
    int bh = blockIdx.y, n0 = blockIdx.x * 256;
    int t = threadIdx.x;
    const ushort* src = vb + ((size_t)bh * NV + n0) * DH;
#pragma unroll
    for (int p = 0; p < 4; ++p) {
        int idx = p * 256 + t;
        int rowi = idx >> 2, ch = idx & 3;
        short8 u = *(const short8*)(src + idx * 8);
        *(short8*)(&Ld[rowi * 40 + ch * 8]) = u;
    }
    __syncthreads();
    int d = t >> 3, nc = (t & 7) * 32;
    ushort* dst = vt + ((size_t)bh * DH + d) * NV + n0 + nc;
#pragma unroll
    for (int p = 0; p < 4; ++p) {
        short8 u;
#pragma unroll
        for (int i = 0; i < 8; ++i) u[i] = (short)Ld[(nc + p * 8 + i) * 40 + d];
        *(short8*)(dst + p * 8) = u;
    }
}

// ---------------- K4: fused flash attention: S=QK^T/sqrt(dh), softmax, O=PV -> obuf ----------------
// grid (16, 32), 256 threads = 4 waves. Wave w owns 16 Q-rows (n0 + w*16 ..). No inter-wave sync.
// Per K-chunk of 128: MFMA S-chunk in regs -> online softmax (row stats in regs, shfl over the
// 16-lane col group) -> P to per-wave LDS tile -> PV MFMA with V^T frags read from vt (L2).
__global__ __launch_bounds__(256) void k_attn(const ushort* __restrict__ qb, const ushort* __restrict__ kb,
                                              const ushort* __restrict__ vt, ushort* __restrict__ obuf) {
    __shared__ ushort Ps[4][16][136];   // per-wave P tile, padded: stride 272B (16B-aligned, 4-way max on write)
    int n0 = blockIdx.x * 64, bh = blockIdx.y;
    int b = bh >> 2, h = bh & 3;
    int t = threadIdx.x, lane = t & 63, w = t >> 6;
    int cl = lane & 15, q = lane >> 4;
    // Q fragment (A operand): row = cl (within wave's 16), k = q*8..+7
    short8 qf = *(const short8*)(qb + ((size_t)bh * NV + n0 + w * 16 + cl) * DH + q * 8);
    const ushort* kbase = kb + (size_t)bh * NV * DH;
    const ushort* vbase = vt + (size_t)bh * DH * NV;
    ushort (*P)[136] = Ps[w];
    const float scale = 0.17677669529663687f;
    float m[4], l[4];
#pragma unroll
    for (int r = 0; r < 4; ++r) { m[r] = -1e30f; l[r] = 0.f; }
    f32x4 oacc[2] = {};                 // O[row=q*4+r][d=j2*16+cl]
#pragma unroll 1
    for (int kt = 0; kt < 8; ++kt) {
        // ---- S chunk: 16 rows x 128 cols, C[row=q*4+r][col=j*16+cl] ----
        f32x4 acc[8] = {};
#pragma unroll
        for (int j = 0; j < 8; ++j) {
            short8 kf = *(const short8*)(kbase + (size_t)(kt * 128 + j * 16 + cl) * DH + q * 8);
            acc[j] = __builtin_amdgcn_mfma_f32_16x16x32_bf16(qf, kf, acc[j], 0, 0, 0);
        }
        // ---- online softmax per row (r), cols spread over j in-thread and cl cross-lane ----
#pragma unroll
        for (int r = 0; r < 4; ++r) {
            float rm = -1e30f;
#pragma unroll
            for (int j = 0; j < 8; ++j) rm = fmaxf(rm, acc[j][r]);
            rm = fmaxf(rm, __shfl_xor(rm, 1));
            rm = fmaxf(rm, __shfl_xor(rm, 2));
            rm = fmaxf(rm, __shfl_xor(rm, 4));
            rm = fmaxf(rm, __shfl_xor(rm, 8));
            rm *= scale;
            float mn = fmaxf(m[r], rm);
            float corr = __expf(m[r] - mn);
            float ps = 0.f;
#pragma unroll
            for (int j = 0; j < 8; ++j) {
                float p = __expf(acc[j][r] * scale - mn);
                acc[j][r] = p;
                ps += p;
            }
            ps += __shfl_xor(ps, 1); ps += __shfl_xor(ps, 2);
            ps += __shfl_xor(ps, 4); ps += __shfl_xor(ps, 8);
            l[r] = l[r] * corr + ps;
            m[r] = mn;
            oacc[0][r] *= corr;
            oacc[1][r] *= corr;
        }
        // ---- P (bf16) -> per-wave LDS: row q*4+r, col j*16+cl (same-wave RAW, compiler waitcnt) ----
#pragma unroll
        for (int j = 0; j < 8; ++j)
#pragma unroll
            for (int r = 0; r < 4; ++r)
                P[q * 4 + r][j * 16 + cl] = f2bf(acc[j][r]);
        // ---- PV: O[16x32] += P[16x128] x V[128x32]; V^T frags straight from vt (L2) ----
#pragma unroll
        for (int ks = 0; ks < 4; ++ks) {
            short8 pf = *(const short8*)(&P[cl][ks * 32 + q * 8]);
#pragma unroll
            for (int j2 = 0; j2 < 2; ++j2) {
                short8 vf = *(const short8*)(vbase + (size_t)(j2 * 16 + cl) * NV + kt * 128 + ks * 32 + q * 8);
                oacc[j2] = __builtin_amdgcn_mfma_f32_16x16x32_bf16(pf, vf, oacc[j2], 0, 0, 0);
            }
        }
    }
    // ---- epilogue: normalize by l, write obuf ----
#pragma unroll
    for (int r = 0; r < 4; ++r) {
        float inv = 1.0f / l[r];
        int row = n0 + w * 16 + q * 4 + r;
        ushort* orow = obuf + ((size_t)(b * NV + row)) * HH + h * DH;
#pragma unroll
        for (int j2 = 0; j2 < 2; ++j2)
            orow[j2 * 16 + cl] = f2bf(oacc[j2][r] * inv);
    }
}

// ---------------- K7: proj (MFMA) + residual -> eig ----------------
__global__ __launch_bounds__(256) void k_enc_proj(const ushort* __restrict__ obuf, const ushort* __restrict__ Wb,
                                                  const float* __restrict__ bias, float* __restrict__ eig) {
    __shared__ ushort As[16384];
    __shared__ ushort Bs[16384];
    int row0 = blockIdx.x * 128;
    int t = threadIdx.x, lane = t & 63, w = t >> 6;
    int wr = w >> 1, wc = w & 1;
#pragma unroll
    for (int p = 0; p < 8; ++p) {
        int ci = w * 8 + p;
        int kt = ci >> 3, rb = ci & 7;
        const ushort* gp = obuf + (size_t)(row0 + rb * 16 + (lane >> 2)) * HH + kt * 32 + (lane & 3) * 8;
        GLDS(gp, As + kt * 4096 + rb * 512);
        GLDS(Wb + WOFF_OUT + ci * 512 + lane * 8, Bs + ci * 512);
    }
    __syncthreads();
    int cl = lane & 15, q = lane >> 4;
    f32x4 acc[4][4] = {};
#pragma unroll
    for (int kt = 0; kt < 4; ++kt) {
        const ushort* ap = As + kt * 4096 + (wr * 64 + cl) * 32 + q * 8;
        const ushort* bp = Bs + kt * 4096 + (wc * 64 + cl) * 32 + q * 8;
        short8 af[4], bfr[4];
#pragma unroll
        for (int i = 0; i < 4; ++i) af[i] = *(const short8*)(ap + i * 512);
#pragma unroll
        for (int j = 0; j < 4; ++j) bfr[j] = *(const short8*)(bp + j * 512);
#pragma unroll
        for (int i = 0; i < 4; ++i)
#pragma unroll
            for (int j = 0; j < 4; ++j)
                acc[i][j] = __builtin_amdgcn_mfma_f32_16x16x32_bf16(af[i], bfr[j], acc[i][j], 0, 0, 0);
    }
#pragma unroll
    for (int j = 0; j < 4; ++j) {
        int col = wc * 64 + j * 16 + cl;
        float bv = bias[col];
#pragma unroll
        for (int i = 0; i < 4; ++i) {
            int rbase = wr * 64 + i * 16 + q * 4;
#pragma unroll
            for (int r = 0; r < 4; ++r) {
                size_t o = (size_t)(row0 + rbase + r) * HH + col;
                eig[o] += acc[i][j][r] + bv;
            }
        }
    }
}

// ---------------- K8: LN2 + FFN1 + gelu + FFN2 + residual (MFMA, fused) ----------------
__global__ __launch_bounds__(256) void k_enc_ffn(float* __restrict__ eig, const float* __restrict__ g,
                                                 const float* __restrict__ be, const ushort* __restrict__ Wb,
                                                 const float* __restrict__ b1, const float* __restrict__ b2) {
    __shared__ ushort As[16384];
    __shared__ ushort Bs[16384];
    int row0 = blockIdx.x * 128;
    int t = threadIdx.x, lane = t & 63, w = t >> 6;
    int wr = w >> 1, wc = w & 1;
    {
        int r = t >> 1, half = t & 1;
        const float4* rowp = (const float4*)(eig + (size_t)(row0 + r) * HH + half * 64);
        float4 v[16];
        float s = 0.f, s2 = 0.f;
#pragma unroll
        for (int i = 0; i < 16; ++i) {
            float4 a = rowp[i]; v[i] = a;
            s += a.x + a.y + a.z + a.w;
            s2 += a.x * a.x + a.y * a.y + a.z * a.z + a.w * a.w;
        }
        s += __shfl_xor(s, 1); s2 += __shfl_xor(s2, 1);
        float mean = s * 0.0078125f;
        float var = s2 * 0.0078125f - mean * mean;
        float rstd = rsqrtf(var + 1e-5f);
        const float4* g4 = (const float4*)(g + half * 64);
        const float4* b4 = (const float4*)(be + half * 64);
#pragma unroll
        for (int ch = 0; ch < 8; ++ch) {
            float4 a = v[2 * ch], bq = v[2 * ch + 1];
            float4 ga = g4[2 * ch], gb = g4[2 * ch + 1];
            float4 ba = b4[2 * ch], bb = b4[2 * ch + 1];
            short8 u;
            u[0] = (short)f2bf((a.x - mean) * rstd * ga.x + ba.x);
            u[1] = (short)f2bf((a.y - mean) * rstd * ga.y + ba.y);
            u[2] = (short)f2bf((a.z - mean) * rstd * ga.z + ba.z);
            u[3] = (short)f2bf((a.w - mean) * rstd * ga.w + ba.w);
            u[4] = (short)f2bf((bq.x - mean) * rstd * gb.x + bb.x);
            u[5] = (short)f2bf((bq.y - mean) * rstd * gb.y + bb.y);
            u[6] = (short)f2bf((bq.z - mean) * rstd * gb.z + bb.z);
            u[7] = (short)f2bf((bq.w - mean) * rstd * gb.w + bb.w);
            int k = half * 64 + ch * 8;
            *(short8*)(As + (k >> 5) * 4096 + r * 32 + (k & 31)) = u;
        }
    }
#pragma unroll
    for (int p = 0; p < 8; ++p) {
        int ci = w * 8 + p;
        GLDS(Wb + WOFF_F1 + ci * 512 + lane * 8, Bs + ci * 512);
    }
    __syncthreads();
    int cl = lane & 15, q = lane >> 4;
    f32x4 acc[4][4] = {};
#pragma unroll
    for (int kt = 0; kt < 4; ++kt) {
        const ushort* ap = As + kt * 4096 + (wr * 64 + cl) * 32 + q * 8;
        const ushort* bp = Bs + kt * 4096 + (wc * 64 + cl) * 32 + q * 8;
        short8 af[4], bfr[4];
#pragma unroll
        for (int i = 0; i < 4; ++i) af[i] = *(const short8*)(ap + i * 512);
#pragma unroll
        for (int j = 0; j < 4; ++j) bfr[j] = *(const short8*)(bp + j * 512);
#pragma unroll
        for (int i = 0; i < 4; ++i)
#pragma unroll
            for (int j = 0; j < 4; ++j)
                acc[i][j] = __builtin_amdgcn_mfma_f32_16x16x32_bf16(af[i], bfr[j], acc[i][j], 0, 0, 0);
    }
    __syncthreads();   // all waves done reading As/Bs
    // h = gelu(acc + b1) -> As (bf16, chunked); restage Bs = W2
#pragma unroll
    for (int j = 0; j < 4; ++j) {
        int col = wc * 64 + j * 16 + cl;
        float bv = b1[col];
        int koff = (col >> 5) * 4096 + (col & 31);
#pragma unroll
        for (int i = 0; i < 4; ++i) {
            int rbase = wr * 64 + i * 16 + q * 4;
#pragma unroll
            for (int r = 0; r < 4; ++r) {
                float a = acc[i][j][r] + bv;
                float ge = 0.5f * a * (1.0f + erff(a * 0.7071067811865475f));
                As[koff + (rbase + r) * 32] = f2bf(ge);
            }
        }
    }
#pragma unroll
    for (int p = 0; p < 8; ++p) {
        int ci = w * 8 + p;
        GLDS(Wb + WOFF_F2 + ci * 512 + lane * 8, Bs + ci * 512);
    }
    __syncthreads();
    f32x4 acc2[4][4] = {};
#pragma unroll
    for (int kt = 0; kt < 4; ++kt) {
        const ushort* ap = As + kt * 4096 + (wr * 64 + cl) * 32 + q * 8;
        const ushort* bp = Bs + kt * 4096 + (wc * 64 + cl) * 32 + q * 8;
        short8 af[4], bfr[4];
#pragma unroll
        for (int i = 0; i < 4; ++i) af[i] = *(const short8*)(ap + i * 512);
#pragma unroll
        for (int j = 0; j < 4; ++j) bfr[j] = *(const short8*)(bp + j * 512);
#pragma unroll
        for (int i = 0; i < 4; ++i)
#pragma unroll
            for (int j = 0; j < 4; ++j)
                acc2[i][j] = __builtin_amdgcn_mfma_f32_16x16x32_bf16(af[i], bfr[j], acc2[i][j], 0, 0, 0);
    }
#pragma unroll
    for (int j = 0; j < 4; ++j) {
        int col = wc * 64 + j * 16 + cl;
        float bv = b2[col];
#pragma unroll
        for (int i = 0; i < 4; ++i) {
            int rbase = wr * 64 + i * 16 + q * 4;
#pragma unroll
            for (int r = 0; r < 4; ++r) {
                size_t o = (size_t)(row0 + rbase + r) * HH + col;
                eig[o] += acc2[i][j][r] + bv;
            }
        }
    }
}

// ---------------- K9: mean pool over N ----------------
__global__ __launch_bounds__(1024) void k_meanpool(const float* __restrict__ eig, float* __restrict__ me) {
    __shared__ float part[8][HH];
    int b = blockIdx.x, t = threadIdx.x;
    int col = t & 127, grp = t >> 7;
    const float* p = eig + (size_t)b * NV * HH + (size_t)grp * 128 * HH + col;
    float s = 0.f;
    for (int n = 0; n < 128; ++n) s += p[(size_t)n * HH];
    part[grp][col] = s;
    __syncthreads();
    if (t < 128) {
        float a = 0.f;
#pragma unroll
        for (int g2 = 0; g2 < 8; ++g2) a += part[g2][t];
        me[b * HH + t] = a * (1.0f / NV);
    }
}

// ---------------- K10: decoders ----------------
__global__ void k_decoders(const float* __restrict__ me,
                           const float* __restrict__ dscW, const float* __restrict__ dscb,
                           const float* __restrict__ dwavW, const float* __restrict__ dwavb,
                           const float* __restrict__ dsclW, const float* __restrict__ dsclb,
                           float* __restrict__ cs, float* __restrict__ cw, float* __restrict__ csc) {
    __shared__ float m[HH];
    __shared__ float s1[NCOE], s2[NCOE];
    __shared__ float sums[2];
    int b = blockIdx.x, t = threadIdx.x;
    m[t] = me[b * HH + t];
    m[t + 64] = me[b * HH + t + 64];
    __syncthreads();
    if (t < NCOE) {
        float a = dscb[t], a2 = dwavb[t];
        const float* w1 = dscW + t * HH;
        const float* w2 = dwavW + t * HH;
        for (int j = 0; j < HH; ++j) { a += m[j] * w1[j]; a2 += m[j] * w2[j]; }
        s1[t] = 1.f / (1.f + __expf(-a));
        s2[t] = 1.f / (1.f + __expf(-a2));
    }
    if (t < NSC) {
        float a = dsclb[t];
        const float* wv = dsclW + t * HH;
        for (int j = 0; j < HH; ++j) a += m[j] * wv[j];
        csc[b * NSC + t] = 5.0f / (1.f + __expf(-a));
    }
    __syncthreads();
    if (t == 0) {
        float a = 0.f, bb = 0.f;
        for (int c = 0; c < NCOE; ++c) { a += s1[c]; bb += s2[c]; }
        sums[0] = a; sums[1] = bb;
    }
    __syncthreads();
    if (t < NCOE) {
        cs[b * NCOE + t] = s1[t] / (sums[0] + 1e-8f);
        cw[b * NCOE + t] = s2[t] / (sums[1] + 1e-8f);
    }
}

// ---------------- K11: Chebyshev -> fsaT [B,5,N] normalized (+ optional sqrt for symmetric GEMM) ----------------
__global__ void k_fsa(const float* __restrict__ ev, const float* __restrict__ cs,
                      const float* __restrict__ cw, const float* __restrict__ csc,
                      float* __restrict__ fsaT, float* __restrict__ fsqT) {
    __shared__ float lcs[NCOE], lcw[NCOE], lsc[NSC];
    int gid = blockIdx.x * 256 + threadIdx.x;
    int b = gid >> 10, n = gid & (NV - 1);
    int t = threadIdx.x;
    if (t < NCOE) { lcs[t] = cs[b * NCOE + t]; lcw[t] = cw[b * NCOE + t]; }
    if (t < NSC) lsc[t] = csc[b * NSC + t];
    __syncthreads();
    float e = ev[gid];
    float x = e - 1.0f;
    float te = 1.f, to = x;
    float a0 = lcs[0] * 0.5f * (1.f - to);
    for (int c = 1; c < NCOE; ++c) {
        te = 2.f * x * to - te;
        to = 2.f * x * te - to;
        a0 += lcs[c] * 0.5f * (1.f - to);
    }
    float aw[NSC];
#pragma unroll
    for (int s = 0; s < NSC; ++s) {
        float f = e * lsc[s];
        if (f > 2.0f) f = 0.0f;
        float y = f - 1.0f;
        float te2 = 1.f, to2 = y, a = 0.f;
        for (int c = 1; c < NCOE; ++c) {
            te2 = 2.f * y * to2 - te2;
            to2 = 2.f * y * te2 - to2;
            a += lcw[c] * 0.5f * (1.f - te2);
        }
        aw[s] = a;
    }
    float n2 = a0 * a0;
#pragma unroll
    for (int s = 0; s < NSC; ++s) n2 += aw[s] * aw[s];
    float inv = 1.f / (sqrtf(n2) + 1e-8f);
    float v0 = a0 * inv;
    fsaT[((size_t)b * 5 + 0) * NV + n] = v0;
    if (fsqT) fsqT[((size_t)b * 5 + 0) * NV + n] = sqrtf(fmaxf(v0, 0.f));
#pragma unroll
    for (int s = 0; s < NSC; ++s) {
        float vs = aw[s] * inv;
        fsaT[((size_t)b * 5 + 1 + s) * NV + n] = vs;
        if (fsqT) fsqT[((size_t)b * 5 + 1 + s) * NV + n] = sqrtf(fmaxf(vs, 0.f));
    }
}

// ---------------- K12: eigenvector f32 -> bf16 (fallback path only) ----------------
__global__ void k_tobf16(const float* __restrict__ in, ushort* __restrict__ outp) {
    int i = blockIdx.x * 256 + threadIdx.x;
    const float4* p = (const float4*)in + (size_t)i * 2;
    float4 a = p[0], bq = p[1];
    uint4 r;
    r.x = (uint)f2bf(a.x) | ((uint)f2bf(a.y) << 16);
    r.y = (uint)f2bf(a.z) | ((uint)f2bf(a.w) << 16);
    r.z = (uint)f2bf(bq.x) | ((uint)f2bf(bq.y) << 16);
    r.w = (uint)f2bf(bq.z) | ((uint)f2bf(bq.w) << 16);
    ((uint4*)outp)[i] = r;
}

// ---------------- K12b: prescale Asc[b][s][n][k] = bf16(V[n,k] * sqrt(fsa[b,s,k])) ----------------
// Global layout is pre-swizzled: granule g (8 consecutive k within each 32-k tile) is stored at
// g ^ ((n>>2)&3) so that linear global_load_lds yields a bank-balanced LDS image (rule #21:
// swizzle on SOURCE + same swizzle on READ, LDS dest stays linear).
__global__ __launch_bounds__(256) void k_prescale(const float* __restrict__ evec, const float* __restrict__ fsq,
                                                  ushort* __restrict__ Asc) {
    int gid = blockIdx.x * 256 + threadIdx.x;     // 8*1024*128 threads: (b, n, granule)
    int gk = gid & 127;
    int n = (gid >> 7) & (NV - 1);
    int b = gid >> 17;
    const float4* vp = (const float4*)(evec + ((size_t)b * NV + n) * NV + gk * 8);
    float4 a = vp[0], c = vp[1];
    int gsw = (gk & ~3) | ((gk ^ (n >> 2)) & 3);
    size_t dstbase = ((size_t)(b * 5) * NV + n) * NV + (size_t)gsw * 8;
#pragma unroll
    for (int s = 0; s < 5; ++s) {
        const float* fp = fsq + (size_t)(b * 5 + s) * NV + gk * 8;
        float4 f0 = *(const float4*)fp, f1 = *(const float4*)(fp + 4);
        uint4 r;
        r.x = (uint)f2bf(a.x * f0.x) | ((uint)f2bf(a.y * f0.y) << 16);
        r.y = (uint)f2bf(a.z * f0.z) | ((uint)f2bf(a.w * f0.w) << 16);
        r.z = (uint)f2bf(c.x * f1.x) | ((uint)f2bf(c.y * f1.y) << 16);
        r.w = (uint)f2bf(c.z * f1.z) | ((uint)f2bf(c.w * f1.w) << 16);
        *(uint4*)(Asc + dstbase + (size_t)s * NV * NV) = r;
    }
}

// ---------------- K13b: symmetric filters GEMM: C = Asc Asc^T, upper-triangular tiles only ----------------
// 2-phase software pipeline: double-buffered LDS, prefetch kt+1 issued before compute of kt,
// ONE barrier per K-step. Writes only the upper tile (mirror produced by k_norm_sym).
__global__ __launch_bounds__(256) void k_gemm_sym(const ushort* __restrict__ Asc,
                                                  float* __restrict__ out,
                                                  float* __restrict__ cn) {
    __shared__ ushort As[2][4096];
    __shared__ ushort Bs[2][4096];
    int lin = blockIdx.x;
    int wg = (lin & 7) * 180 + (lin >> 3);
    int bs = wg / 36, p = wg % 36;
    int b = bs / 5, s = bs % 5;
    int ti = 0, rem = p;
    while (rem >= 8 - ti) { rem -= 8 - ti; ++ti; }
    int tj = ti + rem;
    int n0 = ti * 128, m0 = tj * 128;
    int tid = threadIdx.x, lane = tid & 63, w = tid >> 6;
    int wr = w >> 1, wc = w & 1;
    const ushort* Abase = Asc + (size_t)(b * 5 + s) * NV * NV;
    const ushort* an = Abase + (size_t)n0 * NV;
    const ushort* am = Abase + (size_t)m0 * NV;
    int rrow0 = lane >> 2;
    int kch = (lane & 3) * 8;
    int cl = lane & 15, q = lane >> 4;
    int qx = (q ^ (cl >> 2)) & 3;
    int fo = cl * 32 + qx * 8;

    auto STAGE = [&](int nb, int k0) {
#pragma unroll
        for (int p2 = 0; p2 < 2; ++p2) {
            int ci = w * 2 + p2;
            int rr = ci * 16 + rrow0;
            GLDS(an + (size_t)rr * NV + k0 + kch, &As[nb][ci * 512]);
            GLDS(am + (size_t)rr * NV + k0 + kch, &Bs[nb][ci * 512]);
        }
    };

    f32x4 acc[4][4] = {};
    STAGE(0, 0);
    __syncthreads();
    for (int kt = 0; kt < 31; ++kt) {
        int cur = kt & 1;
        STAGE(cur ^ 1, (kt + 1) * 32);
        short8 af[4], bfr[4];
#pragma unroll
        for (int i = 0; i < 4; ++i) af[i] = *(const short8*)(&As[cur][(wr * 4 + i) * 512 + fo]);
#pragma unroll
        for (int j = 0; j < 4; ++j) bfr[j] = *(const short8*)(&Bs[cur][(wc * 4 + j) * 512 + fo]);
#pragma unroll
        for (int i = 0; i < 4; ++i)
#pragma unroll
            for (int j = 0; j < 4; ++j)
                acc[i][j] = __builtin_amdgcn_mfma_f32_16x16x32_bf16(af[i], bfr[j], acc[i][j], 0, 0, 0);
        __syncthreads();
    }
    {
        short8 af[4], bfr[4];
#pragma unroll
        for (int i = 0; i < 4; ++i) af[i] = *(const short8*)(&As[1][(wr * 4 + i) * 512 + fo]);
#pragma unroll
        for (int j = 0; j < 4; ++j) bfr[j] = *(const short8*)(&Bs[1][(wc * 4 + j) * 512 + fo]);
#pragma unroll
        for (int i = 0; i < 4; ++i)
#pragma unroll
            for (int j = 0; j < 4; ++j)
                acc[i][j] = __builtin_amdgcn_mfma_f32_16x16x32_bf16(af[i], bfr[j], acc[i][j], 0, 0, 0);
    }
    size_t ob = (size_t)(s * BB + b) * NV * NV;
    float* cnb = cn + (size_t)(s * BB + b) * NV;
    float colss[4] = {0.f, 0.f, 0.f, 0.f};
    float rowss[4][4];
#pragma unroll
    for (int i = 0; i < 4; ++i)
#pragma unroll
        for (int r = 0; r < 4; ++r) rowss[i][r] = 0.f;
#pragma unroll
    for (int i = 0; i < 4; ++i) {
        int rbase = n0 + wr * 64 + i * 16 + q * 4;
#pragma unroll
        for (int j = 0; j < 4; ++j) {
            int col = m0 + wc * 64 + j * 16 + cl;
#pragma unroll
            for (int r = 0; r < 4; ++r) {
                float v = acc[i][j][r];
                out[ob + (size_t)(rbase + r) * NV + col] = v;
                colss[j] += v * v;
                rowss[i][r] += v * v;
            }
        }
    }
#pragma unroll
    for (int j = 0; j < 4; ++j) {
        float v = colss[j];
        v += __shfl_xor(v, 16);
        v += __shfl_xor(v, 32);
        if (q == 0) atomicAdd(cnb + (m0 + wc * 64 + j * 16 + cl), v);
    }
    if (ti != tj) {
#pragma unroll
        for (int i = 0; i < 4; ++i)
#pragma unroll
            for (int r = 0; r < 4; ++r) {
                float v = rowss[i][r];
                v += __shfl_xor(v, 1); v += __shfl_xor(v, 2);
                v += __shfl_xor(v, 4); v += __shfl_xor(v, 8);
                if (cl == 0) atomicAdd(cnb + (n0 + wr * 64 + i * 16 + q * 4 + r), v);
            }
    }
}

// ---------------- K13: filters GEMM (fallback path: on-the-fly scaling) ----------------
__global__ __launch_bounds__(256) void k_gemm(const ushort* __restrict__ Vb,
                                              const float* __restrict__ fsaT,
                                              float* __restrict__ out,
                                              float* __restrict__ cn) {
    __shared__ ushort As[128 * 32];
    __shared__ ushort Bs[128 * 32];
    int tile = blockIdx.x;
    int bsid = blockIdx.y;
    int b = bsid / 5, s = bsid % 5;
    int n0 = (tile >> 3) * 128, m0 = (tile & 7) * 128;
    int tid = threadIdx.x, lane = tid & 63, w = tid >> 6;
    int wr = w >> 1, wc = w & 1;
    const ushort* Vbase = Vb + (size_t)b * NV * NV;
    const float* fs = fsaT + ((size_t)b * 5 + s) * NV;
    f32x4 acc[4][4] = {};

    for (int kt = 0; kt < NV / 32; ++kt) {
        int k0 = kt * 32;
        __syncthreads();
#pragma unroll
        for (int p = 0; p < 2; ++p) {
            int ci = w * 2 + p;
            int rrow = ci * 16 + (lane >> 2);
            int kch = (lane & 3) * 8;
            const ushort* gp = Vbase + (size_t)(m0 + rrow) * NV + k0 + kch;
            GLDS(gp, Bs + ci * 512);
        }
#pragma unroll
        for (int p = 0; p < 2; ++p) {
            int idx = p * 256 + tid;
            int rrow = idx >> 2;
            int kch = (idx & 3) * 8;
            const ushort* gp = Vbase + (size_t)(n0 + rrow) * NV + k0 + kch;
            uint4 raw = *(const uint4*)gp;
            const float4* fp = (const float4*)(fs + k0 + kch);
            float4 f0 = fp[0], f1 = fp[1];
            float v0 = __uint_as_float(raw.x << 16) * f0.x;
            float v1 = __uint_as_float(raw.x & 0xffff0000u) * f0.y;
            float v2 = __uint_as_float(raw.y << 16) * f0.z;
            float v3 = __uint_as_float(raw.y & 0xffff0000u) * f0.w;
            float v4 = __uint_as_float(raw.z << 16) * f1.x;
            float v5 = __uint_as_float(raw.z & 0xffff0000u) * f1.y;
            float v6 = __uint_as_float(raw.w << 16) * f1.z;
            float v7 = __uint_as_float(raw.w & 0xffff0000u) * f1.w;
            uint4 rr;
            rr.x = (uint)f2bf(v0) | ((uint)f2bf(v1) << 16);
            rr.y = (uint)f2bf(v2) | ((uint)f2bf(v3) << 16);
            rr.z = (uint)f2bf(v4) | ((uint)f2bf(v5) << 16);
            rr.w = (uint)f2bf(v6) | ((uint)f2bf(v7) << 16);
            *(uint4*)(As + rrow * 32 + kch) = rr;
        }
        __syncthreads();
        int cl = lane & 15, q = lane >> 4;
        const ushort* ap = As + ((wr * 64 + cl) * 32 + q * 8);
        const ushort* bp = Bs + ((wc * 64 + cl) * 32 + q * 8);
        short8 af[4], bfr[4];
#pragma unroll
        for (int i = 0; i < 4; ++i) af[i] = *(const short8*)(ap + i * 512);
#pragma unroll
        for (int j = 0; j < 4; ++j) bfr[j] = *(const short8*)(bp + j * 512);
#pragma unroll
        for (int i = 0; i < 4; ++i)
#pragma unroll
            for (int j = 0; j < 4; ++j)
                acc[i][j] = __builtin_amdgcn_mfma_f32_16x16x32_bf16(af[i], bfr[j], acc[i][j], 0, 0, 0);
    }
    int cl = lane & 15, q = lane >> 4;
    size_t ob = (size_t)(s * BB + b) * NV * NV;
    float colss[4] = {0.f, 0.f, 0.f, 0.f};
#pragma unroll
    for (int i = 0; i < 4; ++i) {
        int rbase = n0 + wr * 64 + i * 16 + q * 4;
#pragma unroll
        for (int j = 0; j < 4; ++j) {
            int col = m0 + wc * 64 + j * 16 + cl;
#pragma unroll
            for (int r = 0; r < 4; ++r) {
                float v = acc[i][j][r];
                out[ob + (size_t)(rbase + r) * NV + col] = v;
                colss[j] += v * v;
            }
        }
    }
    float* cnb = cn + (size_t)(s * BB + b) * NV;
#pragma unroll
    for (int j = 0; j < 4; ++j) {
        float v = colss[j];
        v += __shfl_xor(v, 16);
        v += __shfl_xor(v, 32);
        if (q == 0) atomicAdd(cnb + (m0 + wc * 64 + j * 16 + cl), v);
    }
}

// ---------------- K14b: tile normalization + mirror write (symmetric path) ----------------
__global__ __launch_bounds__(256) void k_norm_sym(float* __restrict__ out, const float* __restrict__ cn) {
    __shared__ float L[128][68];
    int ti = blockIdx.x >> 3, tj = blockIdx.x & 7;
    if (ti > tj) return;
    int bs = blockIdx.y;
    int n0 = ti * 128, m0 = tj * 128;
    size_t ob = (size_t)bs * NV * NV;
    const float* cnb = cn + (size_t)bs * NV;
    int t = threadIdx.x;
#pragma unroll 1
    for (int ch = 0; ch < 2; ++ch) {
        if (ch) __syncthreads();
#pragma unroll
        for (int p = 0; p < 8; ++p) {
            int idx = p * 256 + t;
            int r = idx >> 5;
            int c4 = (idx & 31) * 4;
            size_t o = ob + (size_t)(n0 + ch * 64 + r) * NV + m0 + c4;
            float4 v = *(float4*)(out + o);
            float4 sm = *(const float4*)(cnb + m0 + c4);
            float4 wv;
            wv.x = v.x * (1.f / fmaxf(sqrtf(sm.x), 1e-12f));
            wv.y = v.y * (1.f / fmaxf(sqrtf(sm.y), 1e-12f));
            wv.z = v.z * (1.f / fmaxf(sqrtf(sm.z), 1e-12f));
            wv.w = v.w * (1.f / fmaxf(sqrtf(sm.w), 1e-12f));
            *(float4*)(out + o) = wv;
            if (ti != tj) {
                L[c4 + 0][r] = v.x; L[c4 + 1][r] = v.y;
                L[c4 + 2][r] = v.z; L[c4 + 3][r] = v.w;
            }
        }
        if (ti != tj) {
            __syncthreads();
#pragma unroll
            for (int p = 0; p < 8; ++p) {
                int idx = p * 256 + t;
                int mr = idx >> 4;
                int j4 = (idx & 15) * 4;
                float4 sn = *(const float4*)(cnb + n0 + ch * 64 + j4);
                float4 wv;
                wv.x = L[mr][j4 + 0] * (1.f / fmaxf(sqrtf(sn.x), 1e-12f));
                wv.y = L[mr][j4 + 1] * (1.f / fmaxf(sqrtf(sn.y), 1e-12f));
                wv.z = L[mr][j4 + 2] * (1.f / fmaxf(sqrtf(sn.z), 1e-12f));
                wv.w = L[mr][j4 + 3] * (1.f / fmaxf(sqrtf(sn.w), 1e-12f));
                *(float4*)(out + ob + (size_t)(m0 + mr) * NV + n0 + ch * 64 + j4) = wv;
            }
        }
    }
}

// ---------------- K14: column normalization (fallback path) ----------------
__global__ void k_norm(float* __restrict__ out, const float* __restrict__ cn) {
    int bid = blockIdx.x;
    int bs = bid >> 10, n = bid & (NV - 1);
    int m4 = threadIdx.x * 4;
    float4 ssv = *(const float4*)(cn + (size_t)bs * NV + m4);
    float4* p = (float4*)(out + ((size_t)bs * NV + n) * NV + m4);
    float4 v = *p;
    v.x *= 1.f / fmaxf(sqrtf(ssv.x), 1e-12f);
    v.y *= 1.f / fmaxf(sqrtf(ssv.y), 1e-12f);
    v.z *= 1.f / fmaxf(sqrtf(ssv.z), 1e-12f);
    v.w *= 1.f / fmaxf(sqrtf(ssv.w), 1e-12f);
    *p = v;
}

extern "C" void kernel_launch(void* const* d_in, const int* in_sizes, int n_in,
                              void* d_out, int out_size, void* d_ws, size_t ws_size,
                              hipStream_t stream) {
    const float* eigenvalue = (const float*)d_in[0];
    const float* eigenvector = (const float*)d_in[1];
    const float* eigw_W = (const float*)d_in[2];
    const float* eigw_b = (const float*)d_in[3];
    const float* ln1_g = (const float*)d_in[4];
    const float* ln1_b = (const float*)d_in[5];
    const float* qkv_W = (const float*)d_in[6];
    const float* qkv_b = (const float*)d_in[7];
    const float* out_W = (const float*)d_in[8];
    const float* out_b = (const float*)d_in[9];
    const float* ln2_g = (const float*)d_in[10];
    const float* ln2_b = (const float*)d_in[11];
    const float* ffn1_W = (const float*)d_in[12];
    const float* ffn1_b = (const float*)d_in[13];
    const float* ffn2_W = (const float*)d_in[14];
    const float* ffn2_b = (const float*)d_in[15];
    const float* dsc_W = (const float*)d_in[16];
    const float* dsc_b = (const float*)d_in[17];
    const float* dwav_W = (const float*)d_in[18];
    const float* dwav_b = (const float*)d_in[19];
    const float* dscl_W = (const float*)d_in[20];
    const float* dscl_b = (const float*)d_in[21];

    char* w = (char*)d_ws;
    float* eig  = (float*)(w + 0);             // 4 MB
    float* me   = (float*)(w + 4194304);       // 4 KB
    float* cs   = (float*)(w + 4198400);       // 2 KB
    float* cw   = (float*)(w + 4200448);       // 2 KB
    float* csc  = (float*)(w + 4202496);       // 1 KB
    float* fsaT = (float*)(w + 4203520);       // 160 KB
    float* cn   = (float*)(w + 4367360);       // 160 KB
    ushort* qb  = (ushort*)(w + 4531200);      // 2 MB
    ushort* kb  = (ushort*)(w + 6628352);      // 2 MB
    ushort* vb  = (ushort*)(w + 8725504);      // 2 MB
    ushort* vt  = (ushort*)(w + 10822656);     // 2 MB
    ushort* obuf = (ushort*)(w + 12919808);    // 2 MB
    ushort* Wb  = (ushort*)(w + 15016960);     // 224 KB
    ushort* Vb  = (ushort*)(w + 15246336);     // 16 MB -> end 32,023,552

    // symmetric-GEMM path extras (only touched when ws_size admits them)
    bool big = ws_size >= (size_t)117440512;
    float* fsqT = big ? (float*)(w + 32023552) : nullptr;   // 160 KB
    ushort* Asc = (ushort*)(w + 33554432);                  // 84 MB

    float* outp = (float*)d_out;

    hipMemsetAsync(cn, 0, 40 * NV * sizeof(float), stream);

    k_wcvt<<<dim3(WB_ELEMS / 256), dim3(256), 0, stream>>>(eigw_W, qkv_W, out_W, ffn1_W, ffn2_W, Wb);
    k_enc_sine<<<dim3(64), dim3(256), 0, stream>>>(eigenvalue, Wb, eigw_W, eigw_b, eig);
    k_enc_qkv<<<dim3(64), dim3(256), 0, stream>>>(eig, ln1_g, ln1_b, Wb, qkv_b, qb, kb, vb);
    k_vt<<<dim3(4, 32), dim3(256), 0, stream>>>(vb, vt);
    k_attn<<<dim3(16, 32), dim3(256), 0, stream>>>(qb, kb, vt, obuf);
    k_enc_proj<<<dim3(64), dim3(256), 0, stream>>>(obuf, Wb, out_b, eig);
    k_enc_ffn<<<dim3(64), dim3(256), 0, stream>>>(eig, ln2_g, ln2_b, Wb, ffn1_b, ffn2_b);
    k_meanpool<<<dim3(BB), dim3(1024), 0, stream>>>(eig, me);
    k_decoders<<<dim3(BB), dim3(64), 0, stream>>>(me, dsc_W, dsc_b, dwav_W, dwav_b, dscl_W, dscl_b, cs, cw, csc);
    k_fsa<<<dim3(BB * NV / 256), dim3(256), 0, stream>>>(eigenvalue, cs, cw, csc, fsaT, fsqT);
    if (big) {
        k_prescale<<<dim3(BB * NV * 128 / 256), dim3(256), 0, stream>>>(eigenvector, fsqT, Asc);
        k_gemm_sym<<<dim3(36 * 40), dim3(256), 0, stream>>>(Asc, outp, cn);
        k_norm_sym<<<dim3(64, 40), dim3(256), 0, stream>>>(outp, cn);
    } else {
        k_tobf16<<<dim3(BB * NV * NV / (8 * 256)), dim3(256), 0, stream>>>(eigenvector, Vb);
        k_gemm<<<dim3(64, 40), dim3(256), 0, stream>>>(Vb, fsaT, outp, cn);
        k_norm<<<dim3(40 * NV), dim3(256), 0, stream>>>(outp, cn);
    }
}

// Round 7
// 488.388 us; speedup vs baseline: 1.0767x; 1.0029x over previous
//
#include <hip/hip_runtime.h>
#include <hip/hip_bf16.h>
#include <cstdint>

#define BB 8
#define NV 1024
#define HH 128
#define DH 32
#define NCOE 50
#define NSC 4

// Wb segment offsets (elements)
#define WOFF_EIG 0
#define WOFF_QKV 16384
#define WOFF_OUT 65536
#define WOFF_F1  81920
#define WOFF_F2  98304
#define WB_ELEMS 114688

typedef __attribute__((ext_vector_type(8))) short short8;
typedef __attribute__((ext_vector_type(4))) float f32x4;

__device__ __forceinline__ ushort f2bf(float f) {
    uint32_t x = __float_as_uint(f);
    uint32_t r = x + 0x7FFFu + ((x >> 16) & 1u);
    return (ushort)(r >> 16);
}

#define GLDS(gp, lp) __builtin_amdgcn_global_load_lds((const __attribute__((address_space(1))) void*)(gp), (__attribute__((address_space(3))) void*)(lp), 16, 0, 0)

// ---------------- K0: weight convert f32 -> bf16, LDS-chunked layout [kt][r][32] ----------------
__global__ void k_wcvt(const float* __restrict__ eigw_W, const float* __restrict__ qkv_W,
                       const float* __restrict__ out_W, const float* __restrict__ f1W,
                       const float* __restrict__ f2W, ushort* __restrict__ Wb) {
    int idx = blockIdx.x * 256 + threadIdx.x;
    float v; int dst;
    if (idx < 16384) {                 // eigw cols 1..128
        int r = idx >> 7, k = idx & 127;
        v = eigw_W[r * 129 + 1 + k];
        dst = WOFF_EIG + (k >> 5) * 4096 + r * 32 + (k & 31);
    } else if (idx < 65536) {          // qkv_W, 3 chunks of 128 rows
        int l = idx - 16384; int c = l >> 14, rem = l & 16383;
        int r = rem >> 7, k = rem & 127;
        v = qkv_W[(size_t)(c * 128 + r) * 128 + k];
        dst = WOFF_QKV + c * 16384 + (k >> 5) * 4096 + r * 32 + (k & 31);
    } else if (idx < 81920) {          // out_W
        int l = idx - 65536; int r = l >> 7, k = l & 127;
        v = out_W[r * 128 + k];
        dst = WOFF_OUT + (k >> 5) * 4096 + r * 32 + (k & 31);
    } else if (idx < 98304) {          // ffn1_W
        int l = idx - 81920; int r = l >> 7, k = l & 127;
        v = f1W[r * 128 + k];
        dst = WOFF_F1 + (k >> 5) * 4096 + r * 32 + (k & 31);
    } else {                           // ffn2_W
        int l = idx - 98304; int r = l >> 7, k = l & 127;
        v = f2W[r * 128 + k];
        dst = WOFF_F2 + (k >> 5) * 4096 + r * 32 + (k & 31);
    }
    Wb[dst] = f2bf(v);
}

// ---------------- K1: sine encoding + eigw linear (MFMA) -> eig f32 [8192][128] ----------------
__global__ __launch_bounds__(256) void k_enc_sine(const float* __restrict__ ev, const ushort* __restrict__ Wb,
                                                  const float* __restrict__ eigw_W, const float* __restrict__ eigw_b,
                                                  float* __restrict__ eig) {
    __shared__ ushort As[16384];
    __shared__ ushort Bs[16384];
    int row0 = blockIdx.x * 128;
    int t = threadIdx.x, lane = t & 63, w = t >> 6;
    int wr = w >> 1, wc = w & 1;
#pragma unroll
    for (int p = 0; p < 8; ++p) {
        int ci = w * 8 + p;
        GLDS(Wb + WOFF_EIG + ci * 512 + lane * 8, Bs + ci * 512);
    }
    {
        int r = t >> 1, half = t & 1;
        float e = ev[row0 + r] * 100.0f;
#pragma unroll
        for (int ch = 0; ch < 8; ++ch) {
            short8 u;
#pragma unroll
            for (int l = 0; l < 8; ++l) {
                int j = ch * 8 + l;
                float div = expf((float)(2 * j) * -0.07195578415606394f);
                float pe = e * div;
                u[l] = (short)f2bf(half ? cosf(pe) : sinf(pe));
            }
            int k = half * 64 + ch * 8;
            *(short8*)(As + (k >> 5) * 4096 + r * 32 + (k & 31)) = u;
        }
    }
    __syncthreads();
    int cl = lane & 15, q = lane >> 4;
    f32x4 acc[4][4] = {};
#pragma unroll
    for (int kt = 0; kt < 4; ++kt) {
        const ushort* ap = As + kt * 4096 + (wr * 64 + cl) * 32 + q * 8;
        const ushort* bp = Bs + kt * 4096 + (wc * 64 + cl) * 32 + q * 8;
        short8 af[4], bfr[4];
#pragma unroll
        for (int i = 0; i < 4; ++i) af[i] = *(const short8*)(ap + i * 512);
#pragma unroll
        for (int j = 0; j < 4; ++j) bfr[j] = *(const short8*)(bp + j * 512);
#pragma unroll
        for (int i = 0; i < 4; ++i)
#pragma unroll
            for (int j = 0; j < 4; ++j)
                acc[i][j] = __builtin_amdgcn_mfma_f32_16x16x32_bf16(af[i], bfr[j], acc[i][j], 0, 0, 0);
    }
#pragma unroll
    for (int i = 0; i < 4; ++i) {
        int rbase = wr * 64 + i * 16 + q * 4;
        float er[4];
#pragma unroll
        for (int r = 0; r < 4; ++r) er[r] = ev[row0 + rbase + r];
#pragma unroll
        for (int j = 0; j < 4; ++j) {
            int col = wc * 64 + j * 16 + cl;
            float w0 = eigw_W[col * 129];
            float bv = eigw_b[col];
#pragma unroll
            for (int r = 0; r < 4; ++r)
                eig[(size_t)(row0 + rbase + r) * HH + col] = acc[i][j][r] + er[r] * w0 + bv;
        }
    }
}

// ---------------- K2: LN1 + QKV (MFMA) -> q/k/v bf16 head-major [bh][n][32] ----------------
__global__ __launch_bounds__(256) void k_enc_qkv(const float* __restrict__ eig, const float* __restrict__ g,
                                                 const float* __restrict__ be, const ushort* __restrict__ Wb,
                                                 const float* __restrict__ bias,
                                                 ushort* __restrict__ qb, ushort* __restrict__ kb, ushort* __restrict__ vb) {
    __shared__ ushort As[16384];
    __shared__ ushort Bs[16384];
    int row0 = blockIdx.x * 128;
    int t = threadIdx.x, lane = t & 63, w = t >> 6;
    int wr = w >> 1, wc = w & 1;
    {
        int r = t >> 1, half = t & 1;
        const float4* rowp = (const float4*)(eig + (size_t)(row0 + r) * HH + half * 64);
        float4 v[16];
        float s = 0.f, s2 = 0.f;
#pragma unroll
        for (int i = 0; i < 16; ++i) {
            float4 a = rowp[i]; v[i] = a;
            s += a.x + a.y + a.z + a.w;
            s2 += a.x * a.x + a.y * a.y + a.z * a.z + a.w * a.w;
        }
        s += __shfl_xor(s, 1); s2 += __shfl_xor(s2, 1);
        float mean = s * 0.0078125f;
        float var = s2 * 0.0078125f - mean * mean;
        float rstd = rsqrtf(var + 1e-5f);
        const float4* g4 = (const float4*)(g + half * 64);
        const float4* b4 = (const float4*)(be + half * 64);
#pragma unroll
        for (int ch = 0; ch < 8; ++ch) {
            float4 a = v[2 * ch], b2 = v[2 * ch + 1];
            float4 ga = g4[2 * ch], gb = g4[2 * ch + 1];
            float4 ba = b4[2 * ch], bb = b4[2 * ch + 1];
            short8 u;
            u[0] = (short)f2bf((a.x - mean) * rstd * ga.x + ba.x);
            u[1] = (short)f2bf((a.y - mean) * rstd * ga.y + ba.y);
            u[2] = (short)f2bf((a.z - mean) * rstd * ga.z + ba.z);
            u[3] = (short)f2bf((a.w - mean) * rstd * ga.w + ba.w);
            u[4] = (short)f2bf((b2.x - mean) * rstd * gb.x + bb.x);
            u[5] = (short)f2bf((b2.y - mean) * rstd * gb.y + bb.y);
            u[6] = (short)f2bf((b2.z - mean) * rstd * gb.z + bb.z);
            u[7] = (short)f2bf((b2.w - mean) * rstd * gb.w + bb.w);
            int k = half * 64 + ch * 8;
            *(short8*)(As + (k >> 5) * 4096 + r * 32 + (k & 31)) = u;
        }
    }
    int cl = lane & 15, q = lane >> 4;
    int bidx = row0 >> 10, nbase = row0 & (NV - 1);
    ushort* dsts[3] = {qb, kb, vb};
#pragma unroll 1
    for (int c = 0; c < 3; ++c) {
        __syncthreads();
#pragma unroll
        for (int p = 0; p < 8; ++p) {
            int ci = w * 8 + p;
            GLDS(Wb + WOFF_QKV + c * 16384 + ci * 512 + lane * 8, Bs + ci * 512);
        }
        __syncthreads();
        f32x4 acc[4][4] = {};
#pragma unroll
        for (int kt = 0; kt < 4; ++kt) {
            const ushort* ap = As + kt * 4096 + (wr * 64 + cl) * 32 + q * 8;
            const ushort* bp = Bs + kt * 4096 + (wc * 64 + cl) * 32 + q * 8;
            short8 af[4], bfr[4];
#pragma unroll
            for (int i = 0; i < 4; ++i) af[i] = *(const short8*)(ap + i * 512);
#pragma unroll
            for (int j = 0; j < 4; ++j) bfr[j] = *(const short8*)(bp + j * 512);
#pragma unroll
            for (int i = 0; i < 4; ++i)
#pragma unroll
                for (int j = 0; j < 4; ++j)
                    acc[i][j] = __builtin_amdgcn_mfma_f32_16x16x32_bf16(af[i], bfr[j], acc[i][j], 0, 0, 0);
        }
        ushort* dst = dsts[c];
#pragma unroll
        for (int j = 0; j < 4; ++j) {
            int col = wc * 64 + j * 16 + cl;
            float bv = bias[c * 128 + col];
            int h = col >> 5, dd = col & 31;
            ushort* hb = dst + ((size_t)(bidx * 4 + h) * NV + nbase) * DH + dd;
#pragma unroll
            for (int i = 0; i < 4; ++i) {
                int rbase = wr * 64 + i * 16 + q * 4;
#pragma unroll
                for (int r = 0; r < 4; ++r)
                    hb[(size_t)(rbase + r) * DH] = f2bf(acc[i][j][r] + bv);
            }
        }
    }
}

// ---------------- K3: V transpose -> vt [bh][32][1024] bf16 ----------------
__global__ __launch_bounds__(256) void k_vt(const ushort* __restrict__ vb, ushort* __restrict__ vt) {
    __shared__ ushort Ld[256 * 40];
    int bh = blockIdx.y, n0 = blockIdx.x * 256;
    int t = threadIdx.x;
    const ushort* src = vb + ((size_t)bh * NV + n0) * DH;
#pragma unroll
    for (int p = 0; p < 4; ++p) {
        int idx = p * 256 + t;
        int rowi = idx >> 2, ch = idx & 3;
        short8 u = *(const short8*)(src + idx * 8);
        *(short8*)(&Ld[rowi * 40 + ch * 8]) = u;
    }
    __syncthreads();
    int d = t >> 3, nc = (t & 7) * 32;
    ushort* dst = vt + ((size_t)bh * DH + d) * NV + n0 + nc;
#pragma unroll
    for (int p = 0; p < 4; ++p) {
        short8 u;
#pragma unroll
        for (int i = 0; i < 8; ++i) u[i] = (short)Ld[(nc + p * 8 + i) * 40 + d];
        *(short8*)(dst + p * 8) = u;
    }
}

// ---------------- K4: fused flash attention: S=QK^T/sqrt(dh), softmax, O=PV -> obuf ----------------
// grid (16, 32), 256 threads = 4 waves. Wave w owns 16 Q-rows (n0 + w*16 ..). No inter-wave sync.
// Per K-chunk of 128: MFMA S-chunk in regs -> online softmax (row stats in regs, shfl over the
// 16-lane col group) -> P to per-wave LDS tile -> PV MFMA with V^T frags read from vt (L2).
__global__ __launch_bounds__(256) void k_attn(const ushort* __restrict__ qb, const ushort* __restrict__ kb,
                                              const ushort* __restrict__ vt, ushort* __restrict__ obuf) {
    __shared__ ushort Ps[4][16][136];   // per-wave P tile, padded: stride 272B (16B-aligned, 4-way max on write)
    int n0 = blockIdx.x * 64, bh = blockIdx.y;
    int b = bh >> 2, h = bh & 3;
    int t = threadIdx.x, lane = t & 63, w = t >> 6;
    int cl = lane & 15, q = lane >> 4;
    // Q fragment (A operand): row = cl (within wave's 16), k = q*8..+7
    short8 qf = *(const short8*)(qb + ((size_t)bh * NV + n0 + w * 16 + cl) * DH + q * 8);
    const ushort* kbase = kb + (size_t)bh * NV * DH;
    const ushort* vbase = vt + (size_t)bh * DH * NV;
    ushort (*P)[136] = Ps[w];
    const float scale = 0.17677669529663687f;
    float m[4], l[4];
#pragma unroll
    for (int r = 0; r < 4; ++r) { m[r] = -1e30f; l[r] = 0.f; }
    f32x4 oacc[2] = {};                 // O[row=q*4+r][d=j2*16+cl]
#pragma unroll 1
    for (int kt = 0; kt < 8; ++kt) {
        // ---- S chunk: 16 rows x 128 cols, C[row=q*4+r][col=j*16+cl] ----
        f32x4 acc[8] = {};
#pragma unroll
        for (int j = 0; j < 8; ++j) {
            short8 kf = *(const short8*)(kbase + (size_t)(kt * 128 + j * 16 + cl) * DH + q * 8);
            acc[j] = __builtin_amdgcn_mfma_f32_16x16x32_bf16(qf, kf, acc[j], 0, 0, 0);
        }
        // ---- online softmax per row (r), cols spread over j in-thread and cl cross-lane ----
#pragma unroll
        for (int r = 0; r < 4; ++r) {
            float rm = -1e30f;
#pragma unroll
            for (int j = 0; j < 8; ++j) rm = fmaxf(rm, acc[j][r]);
            rm = fmaxf(rm, __shfl_xor(rm, 1));
            rm = fmaxf(rm, __shfl_xor(rm, 2));
            rm = fmaxf(rm, __shfl_xor(rm, 4));
            rm = fmaxf(rm, __shfl_xor(rm, 8));
            rm *= scale;
            float mn = fmaxf(m[r], rm);
            float corr = __expf(m[r] - mn);
            float ps = 0.f;
#pragma unroll
            for (int j = 0; j < 8; ++j) {
                float p = __expf(acc[j][r] * scale - mn);
                acc[j][r] = p;
                ps += p;
            }
            ps += __shfl_xor(ps, 1); ps += __shfl_xor(ps, 2);
            ps += __shfl_xor(ps, 4); ps += __shfl_xor(ps, 8);
            l[r] = l[r] * corr + ps;
            m[r] = mn;
            oacc[0][r] *= corr;
            oacc[1][r] *= corr;
        }
        // ---- P (bf16) -> per-wave LDS: row q*4+r, col j*16+cl (same-wave RAW, compiler waitcnt) ----
#pragma unroll
        for (int j = 0; j < 8; ++j)
#pragma unroll
            for (int r = 0; r < 4; ++r)
                P[q * 4 + r][j * 16 + cl] = f2bf(acc[j][r]);
        // ---- PV: O[16x32] += P[16x128] x V[128x32]; V^T frags straight from vt (L2) ----
#pragma unroll
        for (int ks = 0; ks < 4; ++ks) {
            short8 pf = *(const short8*)(&P[cl][ks * 32 + q * 8]);
#pragma unroll
            for (int j2 = 0; j2 < 2; ++j2) {
                short8 vf = *(const short8*)(vbase + (size_t)(j2 * 16 + cl) * NV + kt * 128 + ks * 32 + q * 8);
                oacc[j2] = __builtin_amdgcn_mfma_f32_16x16x32_bf16(pf, vf, oacc[j2], 0, 0, 0);
            }
        }
    }
    // ---- epilogue: normalize by l, write obuf ----
#pragma unroll
    for (int r = 0; r < 4; ++r) {
        float inv = 1.0f / l[r];
        int row = n0 + w * 16 + q * 4 + r;
        ushort* orow = obuf + ((size_t)(b * NV + row)) * HH + h * DH;
#pragma unroll
        for (int j2 = 0; j2 < 2; ++j2)
            orow[j2 * 16 + cl] = f2bf(oacc[j2][r] * inv);
    }
}

// ---------------- K7: proj (MFMA) + residual -> eig ----------------
__global__ __launch_bounds__(256) void k_enc_proj(const ushort* __restrict__ obuf, const ushort* __restrict__ Wb,
                                                  const float* __restrict__ bias, float* __restrict__ eig) {
    __shared__ ushort As[16384];
    __shared__ ushort Bs[16384];
    int row0 = blockIdx.x * 128;
    int t = threadIdx.x, lane = t & 63, w = t >> 6;
    int wr = w >> 1, wc = w & 1;
#pragma unroll
    for (int p = 0; p < 8; ++p) {
        int ci = w * 8 + p;
        int kt = ci >> 3, rb = ci & 7;
        const ushort* gp = obuf + (size_t)(row0 + rb * 16 + (lane >> 2)) * HH + kt * 32 + (lane & 3) * 8;
        GLDS(gp, As + kt * 4096 + rb * 512);
        GLDS(Wb + WOFF_OUT + ci * 512 + lane * 8, Bs + ci * 512);
    }
    __syncthreads();
    int cl = lane & 15, q = lane >> 4;
    f32x4 acc[4][4] = {};
#pragma unroll
    for (int kt = 0; kt < 4; ++kt) {
        const ushort* ap = As + kt * 4096 + (wr * 64 + cl) * 32 + q * 8;
        const ushort* bp = Bs + kt * 4096 + (wc * 64 + cl) * 32 + q * 8;
        short8 af[4], bfr[4];
#pragma unroll
        for (int i = 0; i < 4; ++i) af[i] = *(const short8*)(ap + i * 512);
#pragma unroll
        for (int j = 0; j < 4; ++j) bfr[j] = *(const short8*)(bp + j * 512);
#pragma unroll
        for (int i = 0; i < 4; ++i)
#pragma unroll
            for (int j = 0; j < 4; ++j)
                acc[i][j] = __builtin_amdgcn_mfma_f32_16x16x32_bf16(af[i], bfr[j], acc[i][j], 0, 0, 0);
    }
#pragma unroll
    for (int j = 0; j < 4; ++j) {
        int col = wc * 64 + j * 16 + cl;
        float bv = bias[col];
#pragma unroll
        for (int i = 0; i < 4; ++i) {
            int rbase = wr * 64 + i * 16 + q * 4;
#pragma unroll
            for (int r = 0; r < 4; ++r) {
                size_t o = (size_t)(row0 + rbase + r) * HH + col;
                eig[o] += acc[i][j][r] + bv;
            }
        }
    }
}

// ---------------- K8: LN2 + FFN1 + gelu + FFN2 + residual (MFMA, fused) ----------------
__global__ __launch_bounds__(256) void k_enc_ffn(float* __restrict__ eig, const float* __restrict__ g,
                                                 const float* __restrict__ be, const ushort* __restrict__ Wb,
                                                 const float* __restrict__ b1, const float* __restrict__ b2) {
    __shared__ ushort As[16384];
    __shared__ ushort Bs[16384];
    int row0 = blockIdx.x * 128;
    int t = threadIdx.x, lane = t & 63, w = t >> 6;
    int wr = w >> 1, wc = w & 1;
    {
        int r = t >> 1, half = t & 1;
        const float4* rowp = (const float4*)(eig + (size_t)(row0 + r) * HH + half * 64);
        float4 v[16];
        float s = 0.f, s2 = 0.f;
#pragma unroll
        for (int i = 0; i < 16; ++i) {
            float4 a = rowp[i]; v[i] = a;
            s += a.x + a.y + a.z + a.w;
            s2 += a.x * a.x + a.y * a.y + a.z * a.z + a.w * a.w;
        }
        s += __shfl_xor(s, 1); s2 += __shfl_xor(s2, 1);
        float mean = s * 0.0078125f;
        float var = s2 * 0.0078125f - mean * mean;
        float rstd = rsqrtf(var + 1e-5f);
        const float4* g4 = (const float4*)(g + half * 64);
        const float4* b4 = (const float4*)(be + half * 64);
#pragma unroll
        for (int ch = 0; ch < 8; ++ch) {
            float4 a = v[2 * ch], bq = v[2 * ch + 1];
            float4 ga = g4[2 * ch], gb = g4[2 * ch + 1];
            float4 ba = b4[2 * ch], bb = b4[2 * ch + 1];
            short8 u;
            u[0] = (short)f2bf((a.x - mean) * rstd * ga.x + ba.x);
            u[1] = (short)f2bf((a.y - mean) * rstd * ga.y + ba.y);
            u[2] = (short)f2bf((a.z - mean) * rstd * ga.z + ba.z);
            u[3] = (short)f2bf((a.w - mean) * rstd * ga.w + ba.w);
            u[4] = (short)f2bf((bq.x - mean) * rstd * gb.x + bb.x);
            u[5] = (short)f2bf((bq.y - mean) * rstd * gb.y + bb.y);
            u[6] = (short)f2bf((bq.z - mean) * rstd * gb.z + bb.z);
            u[7] = (short)f2bf((bq.w - mean) * rstd * gb.w + bb.w);
            int k = half * 64 + ch * 8;
            *(short8*)(As + (k >> 5) * 4096 + r * 32 + (k & 31)) = u;
        }
    }
#pragma unroll
    for (int p = 0; p < 8; ++p) {
        int ci = w * 8 + p;
        GLDS(Wb + WOFF_F1 + ci * 512 + lane * 8, Bs + ci * 512);
    }
    __syncthreads();
    int cl = lane & 15, q = lane >> 4;
    f32x4 acc[4][4] = {};
#pragma unroll
    for (int kt = 0; kt < 4; ++kt) {
        const ushort* ap = As + kt * 4096 + (wr * 64 + cl) * 32 + q * 8;
        const ushort* bp = Bs + kt * 4096 + (wc * 64 + cl) * 32 + q * 8;
        short8 af[4], bfr[4];
#pragma unroll
        for (int i = 0; i < 4; ++i) af[i] = *(const short8*)(ap + i * 512);
#pragma unroll
        for (int j = 0; j < 4; ++j) bfr[j] = *(const short8*)(bp + j * 512);
#pragma unroll
        for (int i = 0; i < 4; ++i)
#pragma unroll
            for (int j = 0; j < 4; ++j)
                acc[i][j] = __builtin_amdgcn_mfma_f32_16x16x32_bf16(af[i], bfr[j], acc[i][j], 0, 0, 0);
    }
    __syncthreads();   // all waves done reading As/Bs
    // h = gelu(acc + b1) -> As (bf16, chunked); restage Bs = W2
#pragma unroll
    for (int j = 0; j < 4; ++j) {
        int col = wc * 64 + j * 16 + cl;
        float bv = b1[col];
        int koff = (col >> 5) * 4096 + (col & 31);
#pragma unroll
        for (int i = 0; i < 4; ++i) {
            int rbase = wr * 64 + i * 16 + q * 4;
#pragma unroll
            for (int r = 0; r < 4; ++r) {
                float a = acc[i][j][r] + bv;
                float ge = 0.5f * a * (1.0f + erff(a * 0.7071067811865475f));
                As[koff + (rbase + r) * 32] = f2bf(ge);
            }
        }
    }
#pragma unroll
    for (int p = 0; p < 8; ++p) {
        int ci = w * 8 + p;
        GLDS(Wb + WOFF_F2 + ci * 512 + lane * 8, Bs + ci * 512);
    }
    __syncthreads();
    f32x4 acc2[4][4] = {};
#pragma unroll
    for (int kt = 0; kt < 4; ++kt) {
        const ushort* ap = As + kt * 4096 + (wr * 64 + cl) * 32 + q * 8;
        const ushort* bp = Bs + kt * 4096 + (wc * 64 + cl) * 32 + q * 8;
        short8 af[4], bfr[4];
#pragma unroll
        for (int i = 0; i < 4; ++i) af[i] = *(const short8*)(ap + i * 512);
#pragma unroll
        for (int j = 0; j < 4; ++j) bfr[j] = *(const short8*)(bp + j * 512);
#pragma unroll
        for (int i = 0; i < 4; ++i)
#pragma unroll
            for (int j = 0; j < 4; ++j)
                acc2[i][j] = __builtin_amdgcn_mfma_f32_16x16x32_bf16(af[i], bfr[j], acc2[i][j], 0, 0, 0);
    }
#pragma unroll
    for (int j = 0; j < 4; ++j) {
        int col = wc * 64 + j * 16 + cl;
        float bv = b2[col];
#pragma unroll
        for (int i = 0; i < 4; ++i) {
            int rbase = wr * 64 + i * 16 + q * 4;
#pragma unroll
            for (int r = 0; r < 4; ++r) {
                size_t o = (size_t)(row0 + rbase + r) * HH + col;
                eig[o] += acc2[i][j][r] + bv;
            }
        }
    }
}

// ---------------- K9: mean pool over N ----------------
__global__ __launch_bounds__(1024) void k_meanpool(const float* __restrict__ eig, float* __restrict__ me) {
    __shared__ float part[8][HH];
    int b = blockIdx.x, t = threadIdx.x;
    int col = t & 127, grp = t >> 7;
    const float* p = eig + (size_t)b * NV * HH + (size_t)grp * 128 * HH + col;
    float s = 0.f;
    for (int n = 0; n < 128; ++n) s += p[(size_t)n * HH];
    part[grp][col] = s;
    __syncthreads();
    if (t < 128) {
        float a = 0.f;
#pragma unroll
        for (int g2 = 0; g2 < 8; ++g2) a += part[g2][t];
        me[b * HH + t] = a * (1.0f / NV);
    }
}

// ---------------- K10: decoders ----------------
__global__ void k_decoders(const float* __restrict__ me,
                           const float* __restrict__ dscW, const float* __restrict__ dscb,
                           const float* __restrict__ dwavW, const float* __restrict__ dwavb,
                           const float* __restrict__ dsclW, const float* __restrict__ dsclb,
                           float* __restrict__ cs, float* __restrict__ cw, float* __restrict__ csc) {
    __shared__ float m[HH];
    __shared__ float s1[NCOE], s2[NCOE];
    __shared__ float sums[2];
    int b = blockIdx.x, t = threadIdx.x;
    m[t] = me[b * HH + t];
    m[t + 64] = me[b * HH + t + 64];
    __syncthreads();
    if (t < NCOE) {
        float a = dscb[t], a2 = dwavb[t];
        const float* w1 = dscW + t * HH;
        const float* w2 = dwavW + t * HH;
        for (int j = 0; j < HH; ++j) { a += m[j] * w1[j]; a2 += m[j] * w2[j]; }
        s1[t] = 1.f / (1.f + __expf(-a));
        s2[t] = 1.f / (1.f + __expf(-a2));
    }
    if (t < NSC) {
        float a = dsclb[t];
        const float* wv = dsclW + t * HH;
        for (int j = 0; j < HH; ++j) a += m[j] * wv[j];
        csc[b * NSC + t] = 5.0f / (1.f + __expf(-a));
    }
    __syncthreads();
    if (t == 0) {
        float a = 0.f, bb = 0.f;
        for (int c = 0; c < NCOE; ++c) { a += s1[c]; bb += s2[c]; }
        sums[0] = a; sums[1] = bb;
    }
    __syncthreads();
    if (t < NCOE) {
        cs[b * NCOE + t] = s1[t] / (sums[0] + 1e-8f);
        cw[b * NCOE + t] = s2[t] / (sums[1] + 1e-8f);
    }
}

// ---------------- K11: Chebyshev -> fsaT [B,5,N] normalized (+ optional sqrt for symmetric GEMM) ----------------
__global__ void k_fsa(const float* __restrict__ ev, const float* __restrict__ cs,
                      const float* __restrict__ cw, const float* __restrict__ csc,
                      float* __restrict__ fsaT, float* __restrict__ fsqT) {
    __shared__ float lcs[NCOE], lcw[NCOE], lsc[NSC];
    int gid = blockIdx.x * 256 + threadIdx.x;
    int b = gid >> 10, n = gid & (NV - 1);
    int t = threadIdx.x;
    if (t < NCOE) { lcs[t] = cs[b * NCOE + t]; lcw[t] = cw[b * NCOE + t]; }
    if (t < NSC) lsc[t] = csc[b * NSC + t];
    __syncthreads();
    float e = ev[gid];
    float x = e - 1.0f;
    float te = 1.f, to = x;
    float a0 = lcs[0] * 0.5f * (1.f - to);
    for (int c = 1; c < NCOE; ++c) {
        te = 2.f * x * to - te;
        to = 2.f * x * te - to;
        a0 += lcs[c] * 0.5f * (1.f - to);
    }
    float aw[NSC];
#pragma unroll
    for (int s = 0; s < NSC; ++s) {
        float f = e * lsc[s];
        if (f > 2.0f) f = 0.0f;
        float y = f - 1.0f;
        float te2 = 1.f, to2 = y, a = 0.f;
        for (int c = 1; c < NCOE; ++c) {
            te2 = 2.f * y * to2 - te2;
            to2 = 2.f * y * te2 - to2;
            a += lcw[c] * 0.5f * (1.f - te2);
        }
        aw[s] = a;
    }
    float n2 = a0 * a0;
#pragma unroll
    for (int s = 0; s < NSC; ++s) n2 += aw[s] * aw[s];
    float inv = 1.f / (sqrtf(n2) + 1e-8f);
    float v0 = a0 * inv;
    fsaT[((size_t)b * 5 + 0) * NV + n] = v0;
    if (fsqT) fsqT[((size_t)b * 5 + 0) * NV + n] = sqrtf(fmaxf(v0, 0.f));
#pragma unroll
    for (int s = 0; s < NSC; ++s) {
        float vs = aw[s] * inv;
        fsaT[((size_t)b * 5 + 1 + s) * NV + n] = vs;
        if (fsqT) fsqT[((size_t)b * 5 + 1 + s) * NV + n] = sqrtf(fmaxf(vs, 0.f));
    }
}

// ---------------- K12: eigenvector f32 -> bf16 (fallback path only) ----------------
__global__ void k_tobf16(const float* __restrict__ in, ushort* __restrict__ outp) {
    int i = blockIdx.x * 256 + threadIdx.x;
    const float4* p = (const float4*)in + (size_t)i * 2;
    float4 a = p[0], bq = p[1];
    uint4 r;
    r.x = (uint)f2bf(a.x) | ((uint)f2bf(a.y) << 16);
    r.y = (uint)f2bf(a.z) | ((uint)f2bf(a.w) << 16);
    r.z = (uint)f2bf(bq.x) | ((uint)f2bf(bq.y) << 16);
    r.w = (uint)f2bf(bq.z) | ((uint)f2bf(bq.w) << 16);
    ((uint4*)outp)[i] = r;
}

// ---------------- K12b: prescale Asc[b][s][n][k] = bf16(V[n,k] * sqrt(fsa[b,s,k])) ----------------
// Global layout is pre-swizzled: granule g (8 consecutive k within each 32-k tile) is stored at
// g ^ ((n>>2)&3) so that linear global_load_lds yields a bank-balanced LDS image (rule #21:
// swizzle on SOURCE + same swizzle on READ, LDS dest stays linear).
__global__ __launch_bounds__(256) void k_prescale(const float* __restrict__ evec, const float* __restrict__ fsq,
                                                  ushort* __restrict__ Asc) {
    int gid = blockIdx.x * 256 + threadIdx.x;     // 8*1024*128 threads: (b, n, granule)
    int gk = gid & 127;
    int n = (gid >> 7) & (NV - 1);
    int b = gid >> 17;
    const float4* vp = (const float4*)(evec + ((size_t)b * NV + n) * NV + gk * 8);
    float4 a = vp[0], c = vp[1];
    int gsw = (gk & ~3) | ((gk ^ (n >> 2)) & 3);
    size_t dstbase = ((size_t)(b * 5) * NV + n) * NV + (size_t)gsw * 8;
#pragma unroll
    for (int s = 0; s < 5; ++s) {
        const float* fp = fsq + (size_t)(b * 5 + s) * NV + gk * 8;
        float4 f0 = *(const float4*)fp, f1 = *(const float4*)(fp + 4);
        uint4 r;
        r.x = (uint)f2bf(a.x * f0.x) | ((uint)f2bf(a.y * f0.y) << 16);
        r.y = (uint)f2bf(a.z * f0.z) | ((uint)f2bf(a.w * f0.w) << 16);
        r.z = (uint)f2bf(c.x * f1.x) | ((uint)f2bf(c.y * f1.y) << 16);
        r.w = (uint)f2bf(c.z * f1.z) | ((uint)f2bf(c.w * f1.w) << 16);
        *(uint4*)(Asc + dstbase + (size_t)s * NV * NV) = r;
    }
}

// ---------------- K13b: symmetric filters GEMM: C = Asc Asc^T, 256x256 upper tiles ----------------
// 1024 threads = 16 waves (4x4 grid, 64x64 per wave). BK=32, double-buffered 64 KB LDS,
// 2-phase pipeline (prefetch kt+1 before compute of kt, one barrier per K-step).
// 4x4 tile grid per (b,s): 10 upper tiles; diagonal tile's col-sums cover all 4 ordered
// 128-block pairs exactly once; off-diag adds row-sums for the mirror. Mirror C produced later
// by k_norm_sym (128-tile granularity; diagonal-256's lower 128-subtile overwrite is bit-exact).
__global__ __launch_bounds__(1024, 4) void k_gemm_sym(const ushort* __restrict__ Asc,
                                                      float* __restrict__ out,
                                                      float* __restrict__ cn) {
    __shared__ ushort As[2][8192];
    __shared__ ushort Bs[2][8192];
    // bijective XCD swizzle over 400 blocks (400 % 8 == 0): each XCD gets 50 consecutive
    // work ids = 5 complete (b,s) groups -> (b,s)'s 2MB operand stays in one XCD L2.
    int lin = blockIdx.x;
    int wg = (lin & 7) * 50 + (lin >> 3);
    int bs = wg / 10, p = wg % 10;
    int b = bs / 5, s = bs % 5;
    int ti = 0, rem = p;
    while (rem >= 4 - ti) { rem -= 4 - ti; ++ti; }
    int tj = ti + rem;
    int n0 = ti * 256, m0 = tj * 256;
    int tid = threadIdx.x, lane = tid & 63, w = tid >> 6;   // w: 0..15
    int wr = w >> 2, wc = w & 3;
    const ushort* Abase = Asc + (size_t)(b * 5 + s) * NV * NV;
    const ushort* an = Abase + (size_t)n0 * NV;
    const ushort* am = Abase + (size_t)m0 * NV;
    int srow = tid >> 2;                 // 0..255 (staging row)
    int sg = tid & 3;                    // granule within k-tile
    int cl = lane & 15, q = lane >> 4;
    int qx = (q ^ (cl >> 2)) & 3;        // un-swizzle on read (matches k_prescale's granule XOR)
    int fo = cl * 32 + qx * 8;

    auto STAGE = [&](int nb, int k0) {
        GLDS(an + (size_t)srow * NV + k0 + sg * 8, &As[nb][tid * 8]);
        GLDS(am + (size_t)srow * NV + k0 + sg * 8, &Bs[nb][tid * 8]);
    };

    f32x4 acc[4][4] = {};
    STAGE(0, 0);
    __syncthreads();                     // vmcnt(0) drain: buf0 ready
    for (int kt = 0; kt < 31; ++kt) {
        int cur = kt & 1;
        STAGE(cur ^ 1, (kt + 1) * 32);   // prefetch next K-step
        short8 af[4], bfr[4];
#pragma unroll
        for (int i = 0; i < 4; ++i) af[i] = *(const short8*)(&As[cur][(wr * 64 + i * 16 + cl) * 32 + qx * 8]);
#pragma unroll
        for (int j = 0; j < 4; ++j) bfr[j] = *(const short8*)(&Bs[cur][(wc * 64 + j * 16 + cl) * 32 + qx * 8]);
#pragma unroll
        for (int i = 0; i < 4; ++i)
#pragma unroll
            for (int j = 0; j < 4; ++j)
                acc[i][j] = __builtin_amdgcn_mfma_f32_16x16x32_bf16(af[i], bfr[j], acc[i][j], 0, 0, 0);
        __syncthreads();                 // next buf staged + all waves done reading cur
    }
    {   // epilogue K-step: kt = 31 from buffer 1, no prefetch
        short8 af[4], bfr[4];
#pragma unroll
        for (int i = 0; i < 4; ++i) af[i] = *(const short8*)(&As[1][(wr * 64 + i * 16 + cl) * 32 + qx * 8]);
#pragma unroll
        for (int j = 0; j < 4; ++j) bfr[j] = *(const short8*)(&Bs[1][(wc * 64 + j * 16 + cl) * 32 + qx * 8]);
#pragma unroll
        for (int i = 0; i < 4; ++i)
#pragma unroll
            for (int j = 0; j < 4; ++j)
                acc[i][j] = __builtin_amdgcn_mfma_f32_16x16x32_bf16(af[i], bfr[j], acc[i][j], 0, 0, 0);
    }
    size_t ob = (size_t)(s * BB + b) * NV * NV;
    float* cnb = cn + (size_t)(s * BB + b) * NV;
    float colss[4] = {0.f, 0.f, 0.f, 0.f};
#pragma unroll
    for (int i = 0; i < 4; ++i) {
        int rbase = n0 + wr * 64 + i * 16 + q * 4;
#pragma unroll
        for (int r = 0; r < 4; ++r) {
            float rowacc = 0.f;
#pragma unroll
            for (int j = 0; j < 4; ++j) {
                int col = m0 + wc * 64 + j * 16 + cl;
                float v = acc[i][j][r];
                out[ob + (size_t)(rbase + r) * NV + col] = v;
                colss[j] += v * v;
                rowacc += v * v;
            }
            if (ti != tj) {
                rowacc += __shfl_xor(rowacc, 1); rowacc += __shfl_xor(rowacc, 2);
                rowacc += __shfl_xor(rowacc, 4); rowacc += __shfl_xor(rowacc, 8);
                if (cl == 0) atomicAdd(cnb + rbase + r, rowacc);
            }
        }
    }
    // column sums of this tile -> cn[m-range]
#pragma unroll
    for (int j = 0; j < 4; ++j) {
        float v = colss[j];
        v += __shfl_xor(v, 16);
        v += __shfl_xor(v, 32);
        if (q == 0) atomicAdd(cnb + (m0 + wc * 64 + j * 16 + cl), v);
    }
}

// ---------------- K13: filters GEMM (fallback path: on-the-fly scaling) ----------------
__global__ __launch_bounds__(256) void k_gemm(const ushort* __restrict__ Vb,
                                              const float* __restrict__ fsaT,
                                              float* __restrict__ out,
                                              float* __restrict__ cn) {
    __shared__ ushort As[128 * 32];
    __shared__ ushort Bs[128 * 32];
    int tile = blockIdx.x;
    int bsid = blockIdx.y;
    int b = bsid / 5, s = bsid % 5;
    int n0 = (tile >> 3) * 128, m0 = (tile & 7) * 128;
    int tid = threadIdx.x, lane = tid & 63, w = tid >> 6;
    int wr = w >> 1, wc = w & 1;
    const ushort* Vbase = Vb + (size_t)b * NV * NV;
    const float* fs = fsaT + ((size_t)b * 5 + s) * NV;
    f32x4 acc[4][4] = {};

    for (int kt = 0; kt < NV / 32; ++kt) {
        int k0 = kt * 32;
        __syncthreads();
#pragma unroll
        for (int p = 0; p < 2; ++p) {
            int ci = w * 2 + p;
            int rrow = ci * 16 + (lane >> 2);
            int kch = (lane & 3) * 8;
            const ushort* gp = Vbase + (size_t)(m0 + rrow) * NV + k0 + kch;
            GLDS(gp, Bs + ci * 512);
        }
#pragma unroll
        for (int p = 0; p < 2; ++p) {
            int idx = p * 256 + tid;
            int rrow = idx >> 2;
            int kch = (idx & 3) * 8;
            const ushort* gp = Vbase + (size_t)(n0 + rrow) * NV + k0 + kch;
            uint4 raw = *(const uint4*)gp;
            const float4* fp = (const float4*)(fs + k0 + kch);
            float4 f0 = fp[0], f1 = fp[1];
            float v0 = __uint_as_float(raw.x << 16) * f0.x;
            float v1 = __uint_as_float(raw.x & 0xffff0000u) * f0.y;
            float v2 = __uint_as_float(raw.y << 16) * f0.z;
            float v3 = __uint_as_float(raw.y & 0xffff0000u) * f0.w;
            float v4 = __uint_as_float(raw.z << 16) * f1.x;
            float v5 = __uint_as_float(raw.z & 0xffff0000u) * f1.y;
            float v6 = __uint_as_float(raw.w << 16) * f1.z;
            float v7 = __uint_as_float(raw.w & 0xffff0000u) * f1.w;
            uint4 rr;
            rr.x = (uint)f2bf(v0) | ((uint)f2bf(v1) << 16);
            rr.y = (uint)f2bf(v2) | ((uint)f2bf(v3) << 16);
            rr.z = (uint)f2bf(v4) | ((uint)f2bf(v5) << 16);
            rr.w = (uint)f2bf(v6) | ((uint)f2bf(v7) << 16);
            *(uint4*)(As + rrow * 32 + kch) = rr;
        }
        __syncthreads();
        int cl = lane & 15, q = lane >> 4;
        const ushort* ap = As + ((wr * 64 + cl) * 32 + q * 8);
        const ushort* bp = Bs + ((wc * 64 + cl) * 32 + q * 8);
        short8 af[4], bfr[4];
#pragma unroll
        for (int i = 0; i < 4; ++i) af[i] = *(const short8*)(ap + i * 512);
#pragma unroll
        for (int j = 0; j < 4; ++j) bfr[j] = *(const short8*)(bp + j * 512);
#pragma unroll
        for (int i = 0; i < 4; ++i)
#pragma unroll
            for (int j = 0; j < 4; ++j)
                acc[i][j] = __builtin_amdgcn_mfma_f32_16x16x32_bf16(af[i], bfr[j], acc[i][j], 0, 0, 0);
    }
    int cl = lane & 15, q = lane >> 4;
    size_t ob = (size_t)(s * BB + b) * NV * NV;
    float colss[4] = {0.f, 0.f, 0.f, 0.f};
#pragma unroll
    for (int i = 0; i < 4; ++i) {
        int rbase = n0 + wr * 64 + i * 16 + q * 4;
#pragma unroll
        for (int j = 0; j < 4; ++j) {
            int col = m0 + wc * 64 + j * 16 + cl;
#pragma unroll
            for (int r = 0; r < 4; ++r) {
                float v = acc[i][j][r];
                out[ob + (size_t)(rbase + r) * NV + col] = v;
                colss[j] += v * v;
            }
        }
    }
    float* cnb = cn + (size_t)(s * BB + b) * NV;
#pragma unroll
    for (int j = 0; j < 4; ++j) {
        float v = colss[j];
        v += __shfl_xor(v, 16);
        v += __shfl_xor(v, 32);
        if (q == 0) atomicAdd(cnb + (m0 + wc * 64 + j * 16 + cl), v);
    }
}

// ---------------- K14b: tile normalization + mirror write (symmetric path) ----------------
__global__ __launch_bounds__(256) void k_norm_sym(float* __restrict__ out, const float* __restrict__ cn) {
    __shared__ float L[128][68];
    int ti = blockIdx.x >> 3, tj = blockIdx.x & 7;
    if (ti > tj) return;
    int bs = blockIdx.y;
    int n0 = ti * 128, m0 = tj * 128;
    size_t ob = (size_t)bs * NV * NV;
    const float* cnb = cn + (size_t)bs * NV;
    int t = threadIdx.x;
#pragma unroll 1
    for (int ch = 0; ch < 2; ++ch) {
        if (ch) __syncthreads();
#pragma unroll
        for (int p = 0; p < 8; ++p) {
            int idx = p * 256 + t;
            int r = idx >> 5;
            int c4 = (idx & 31) * 4;
            size_t o = ob + (size_t)(n0 + ch * 64 + r) * NV + m0 + c4;
            float4 v = *(float4*)(out + o);
            float4 sm = *(const float4*)(cnb + m0 + c4);
            float4 wv;
            wv.x = v.x * (1.f / fmaxf(sqrtf(sm.x), 1e-12f));
            wv.y = v.y * (1.f / fmaxf(sqrtf(sm.y), 1e-12f));
            wv.z = v.z * (1.f / fmaxf(sqrtf(sm.z), 1e-12f));
            wv.w = v.w * (1.f / fmaxf(sqrtf(sm.w), 1e-12f));
            *(float4*)(out + o) = wv;
            if (ti != tj) {
                L[c4 + 0][r] = v.x; L[c4 + 1][r] = v.y;
                L[c4 + 2][r] = v.z; L[c4 + 3][r] = v.w;
            }
        }
        if (ti != tj) {
            __syncthreads();
#pragma unroll
            for (int p = 0; p < 8; ++p) {
                int idx = p * 256 + t;
                int mr = idx >> 4;
                int j4 = (idx & 15) * 4;
                float4 sn = *(const float4*)(cnb + n0 + ch * 64 + j4);
                float4 wv;
                wv.x = L[mr][j4 + 0] * (1.f / fmaxf(sqrtf(sn.x), 1e-12f));
                wv.y = L[mr][j4 + 1] * (1.f / fmaxf(sqrtf(sn.y), 1e-12f));
                wv.z = L[mr][j4 + 2] * (1.f / fmaxf(sqrtf(sn.z), 1e-12f));
                wv.w = L[mr][j4 + 3] * (1.f / fmaxf(sqrtf(sn.w), 1e-12f));
                *(float4*)(out + ob + (size_t)(m0 + mr) * NV + n0 + ch * 64 + j4) = wv;
            }
        }
    }
}

// ---------------- K14: column normalization (fallback path) ----------------
__global__ void k_norm(float* __restrict__ out, const float* __restrict__ cn) {
    int bid = blockIdx.x;
    int bs = bid >> 10, n = bid & (NV - 1);
    int m4 = threadIdx.x * 4;
    float4 ssv = *(const float4*)(cn + (size_t)bs * NV + m4);
    float4* p = (float4*)(out + ((size_t)bs * NV + n) * NV + m4);
    float4 v = *p;
    v.x *= 1.f / fmaxf(sqrtf(ssv.x), 1e-12f);
    v.y *= 1.f / fmaxf(sqrtf(ssv.y), 1e-12f);
    v.z *= 1.f / fmaxf(sqrtf(ssv.z), 1e-12f);
    v.w *= 1.f / fmaxf(sqrtf(ssv.w), 1e-12f);
    *p = v;
}

extern "C" void kernel_launch(void* const* d_in, const int* in_sizes, int n_in,
                              void* d_out, int out_size, void* d_ws, size_t ws_size,
                              hipStream_t stream) {
    const float* eigenvalue = (const float*)d_in[0];
    const float* eigenvector = (const float*)d_in[1];
    const float* eigw_W = (const float*)d_in[2];
    const float* eigw_b = (const float*)d_in[3];
    const float* ln1_g = (const float*)d_in[4];
    const float* ln1_b = (const float*)d_in[5];
    const float* qkv_W = (const float*)d_in[6];
    const float* qkv_b = (const float*)d_in[7];
    const float* out_W = (const float*)d_in[8];
    const float* out_b = (const float*)d_in[9];
    const float* ln2_g = (const float*)d_in[10];
    const float* ln2_b = (const float*)d_in[11];
    const float* ffn1_W = (const float*)d_in[12];
    const float* ffn1_b = (const float*)d_in[13];
    const float* ffn2_W = (const float*)d_in[14];
    const float* ffn2_b = (const float*)d_in[15];
    const float* dsc_W = (const float*)d_in[16];
    const float* dsc_b = (const float*)d_in[17];
    const float* dwav_W = (const float*)d_in[18];
    const float* dwav_b = (const float*)d_in[19];
    const float* dscl_W = (const float*)d_in[20];
    const float* dscl_b = (const float*)d_in[21];

    char* w = (char*)d_ws;
    float* eig  = (float*)(w + 0);             // 4 MB
    float* me   = (float*)(w + 4194304);       // 4 KB
    float* cs   = (float*)(w + 4198400);       // 2 KB
    float* cw   = (float*)(w + 4200448);       // 2 KB
    float* csc  = (float*)(w + 4202496);       // 1 KB
    float* fsaT = (float*)(w + 4203520);       // 160 KB
    float* cn   = (float*)(w + 4367360);       // 160 KB
    ushort* qb  = (ushort*)(w + 4531200);      // 2 MB
    ushort* kb  = (ushort*)(w + 6628352);      // 2 MB
    ushort* vb  = (ushort*)(w + 8725504);      // 2 MB
    ushort* vt  = (ushort*)(w + 10822656);     // 2 MB
    ushort* obuf = (ushort*)(w + 12919808);    // 2 MB
    ushort* Wb  = (ushort*)(w + 15016960);     // 224 KB
    ushort* Vb  = (ushort*)(w + 15246336);     // 16 MB -> end 32,023,552

    // symmetric-GEMM path extras (only touched when ws_size admits them)
    bool big = ws_size >= (size_t)117440512;
    float* fsqT = big ? (float*)(w + 32023552) : nullptr;   // 160 KB
    ushort* Asc = (ushort*)(w + 33554432);                  // 84 MB

    float* outp = (float*)d_out;

    hipMemsetAsync(cn, 0, 40 * NV * sizeof(float), stream);

    k_wcvt<<<dim3(WB_ELEMS / 256), dim3(256), 0, stream>>>(eigw_W, qkv_W, out_W, ffn1_W, ffn2_W, Wb);
    k_enc_sine<<<dim3(64), dim3(256), 0, stream>>>(eigenvalue, Wb, eigw_W, eigw_b, eig);
    k_enc_qkv<<<dim3(64), dim3(256), 0, stream>>>(eig, ln1_g, ln1_b, Wb, qkv_b, qb, kb, vb);
    k_vt<<<dim3(4, 32), dim3(256), 0, stream>>>(vb, vt);
    k_attn<<<dim3(16, 32), dim3(256), 0, stream>>>(qb, kb, vt, obuf);
    k_enc_proj<<<dim3(64), dim3(256), 0, stream>>>(obuf, Wb, out_b, eig);
    k_enc_ffn<<<dim3(64), dim3(256), 0, stream>>>(eig, ln2_g, ln2_b, Wb, ffn1_b, ffn2_b);
    k_meanpool<<<dim3(BB), dim3(1024), 0, stream>>>(eig, me);
    k_decoders<<<dim3(BB), dim3(64), 0, stream>>>(me, dsc_W, dsc_b, dwav_W, dwav_b, dscl_W, dscl_b, cs, cw, csc);
    k_fsa<<<dim3(BB * NV / 256), dim3(256), 0, stream>>>(eigenvalue, cs, cw, csc, fsaT, fsqT);
    if (big) {
        k_prescale<<<dim3(BB * NV * 128 / 256), dim3(256), 0, stream>>>(eigenvector, fsqT, Asc);
        k_gemm_sym<<<dim3(10 * 40), dim3(1024), 0, stream>>>(Asc, outp, cn);
        k_norm_sym<<<dim3(64, 40), dim3(256), 0, stream>>>(outp, cn);
    } else {
        k_tobf16<<<dim3(BB * NV * NV / (8 * 256)), dim3(256), 0, stream>>>(eigenvector, Vb);
        k_gemm<<<dim3(64, 40), dim3(256), 0, stream>>>(Vb, fsaT, outp, cn);
        k_norm<<<dim3(40 * NV), dim3(256), 0, stream>>>(outp, cn);
    }
}